// Round 1
// baseline (1362.955 us; speedup 1.0000x reference)
//
#include <hip/hip_runtime.h>

#define S_LEN 1024
#define B_SZ 2
#define H_DIM 4096
#define NHEADS 32
#define KVHEADS 8
#define HDIM 128
#define KV_DIM 1024
#define BS_C 2048

typedef short bf8 __attribute__((ext_vector_type(8)));
typedef float f4 __attribute__((ext_vector_type(4)));

static __device__ __forceinline__ unsigned short f2bf(float x) {
  unsigned int u = __float_as_uint(x);
  u += 0x7fffu + ((u >> 16) & 1u);
  return (unsigned short)(u >> 16);
}
static __device__ __forceinline__ float bf2f(unsigned short h) {
  return __uint_as_float(((unsigned int)h) << 16);
}

// ---------------- GEMM: C[M,N] = A[M,K] @ B[N,K]^T (both K-major) ----------
// SPLIT: hi/lo bf16 decomposition for ~fp32 accuracy (used for K/V proj).
// ABF16: A is already bf16 (attention output), B always fp32 source.
template<bool SPLIT, bool ABF16>
__global__ __launch_bounds__(256) void gemm_bt(const void* __restrict__ Ap,
                                               const float* __restrict__ Bp,
                                               float* __restrict__ Cp,
                                               int M, int N, int K) {
  __shared__ short Ah[128 * 40];
  __shared__ short Bh[128 * 40];
  __shared__ short Al[SPLIT ? 128 * 40 : 8];
  __shared__ short Bl[SPLIT ? 128 * 40 : 8];

  const int tid = threadIdx.x;
  const int wid = tid >> 6;
  const int lane = tid & 63;
  const int ln = lane & 15;
  const int quad = lane >> 4;
  const int wx = wid & 1, wy = wid >> 1;
  const int m0 = blockIdx.y * 128, n0 = blockIdx.x * 128;
  const int srow = tid >> 1, shalf = tid & 1;

  f4 acc[4][4];
#pragma unroll
  for (int i = 0; i < 4; i++)
#pragma unroll
    for (int j = 0; j < 4; j++) acc[i][j] = (f4){0.f, 0.f, 0.f, 0.f};

  for (int kk = 0; kk < K; kk += 32) {
    // ---- stage A tile (128 x 32) ----
    if (ABF16) {
      const unsigned short* A16 = (const unsigned short*)Ap;
      const unsigned short* src = A16 + (size_t)(m0 + srow) * K + kk + shalf * 16;
      uint4 a0 = *(const uint4*)(src);
      uint4 a1 = *(const uint4*)(src + 8);
      *(uint4*)&Ah[srow * 40 + shalf * 16] = a0;
      *(uint4*)&Ah[srow * 40 + shalf * 16 + 8] = a1;
    } else {
      const float* A32 = (const float*)Ap;
      const float* src = A32 + (size_t)(m0 + srow) * K + kk + shalf * 16;
      float xs[16];
      *(float4*)&xs[0]  = *(const float4*)(src);
      *(float4*)&xs[4]  = *(const float4*)(src + 4);
      *(float4*)&xs[8]  = *(const float4*)(src + 8);
      *(float4*)&xs[12] = *(const float4*)(src + 12);
      unsigned short hi[16], lo[16];
#pragma unroll
      for (int j = 0; j < 16; j++) {
        hi[j] = f2bf(xs[j]);
        if (SPLIT) lo[j] = f2bf(xs[j] - bf2f(hi[j]));
      }
      *(uint4*)&Ah[srow * 40 + shalf * 16]     = *(uint4*)&hi[0];
      *(uint4*)&Ah[srow * 40 + shalf * 16 + 8] = *(uint4*)&hi[8];
      if (SPLIT) {
        *(uint4*)&Al[srow * 40 + shalf * 16]     = *(uint4*)&lo[0];
        *(uint4*)&Al[srow * 40 + shalf * 16 + 8] = *(uint4*)&lo[8];
      }
    }
    // ---- stage B tile (128 x 32), fp32 source ----
    {
      const float* src = Bp + (size_t)(n0 + srow) * K + kk + shalf * 16;
      float xs[16];
      *(float4*)&xs[0]  = *(const float4*)(src);
      *(float4*)&xs[4]  = *(const float4*)(src + 4);
      *(float4*)&xs[8]  = *(const float4*)(src + 8);
      *(float4*)&xs[12] = *(const float4*)(src + 12);
      unsigned short hi[16], lo[16];
#pragma unroll
      for (int j = 0; j < 16; j++) {
        hi[j] = f2bf(xs[j]);
        if (SPLIT) lo[j] = f2bf(xs[j] - bf2f(hi[j]));
      }
      *(uint4*)&Bh[srow * 40 + shalf * 16]     = *(uint4*)&hi[0];
      *(uint4*)&Bh[srow * 40 + shalf * 16 + 8] = *(uint4*)&hi[8];
      if (SPLIT) {
        *(uint4*)&Bl[srow * 40 + shalf * 16]     = *(uint4*)&lo[0];
        *(uint4*)&Bl[srow * 40 + shalf * 16 + 8] = *(uint4*)&lo[8];
      }
    }
    __syncthreads();

    bf8 af[4], bfr[4], afl[4], bfl[4];
#pragma unroll
    for (int mi = 0; mi < 4; mi++)
      af[mi] = *(const bf8*)&Ah[(wy * 64 + mi * 16 + ln) * 40 + quad * 8];
#pragma unroll
    for (int ni = 0; ni < 4; ni++)
      bfr[ni] = *(const bf8*)&Bh[(wx * 64 + ni * 16 + ln) * 40 + quad * 8];
    if (SPLIT) {
#pragma unroll
      for (int mi = 0; mi < 4; mi++)
        afl[mi] = *(const bf8*)&Al[(wy * 64 + mi * 16 + ln) * 40 + quad * 8];
#pragma unroll
      for (int ni = 0; ni < 4; ni++)
        bfl[ni] = *(const bf8*)&Bl[(wx * 64 + ni * 16 + ln) * 40 + quad * 8];
    }
#pragma unroll
    for (int mi = 0; mi < 4; mi++)
#pragma unroll
      for (int ni = 0; ni < 4; ni++) {
        acc[mi][ni] = __builtin_amdgcn_mfma_f32_16x16x32_bf16(af[mi], bfr[ni], acc[mi][ni], 0, 0, 0);
        if (SPLIT) {
          acc[mi][ni] = __builtin_amdgcn_mfma_f32_16x16x32_bf16(af[mi], bfl[ni], acc[mi][ni], 0, 0, 0);
          acc[mi][ni] = __builtin_amdgcn_mfma_f32_16x16x32_bf16(afl[mi], bfr[ni], acc[mi][ni], 0, 0, 0);
        }
      }
    __syncthreads();
  }

  // epilogue: C/D layout col=lane&15, row=quad*4+reg
#pragma unroll
  for (int mi = 0; mi < 4; mi++) {
    int m = m0 + wy * 64 + mi * 16 + quad * 4;
#pragma unroll
    for (int ni = 0; ni < 4; ni++) {
      int n = n0 + wx * 64 + ni * 16 + ln;
      float* cp = Cp + (size_t)m * N + n;
#pragma unroll
      for (int r = 0; r < 4; r++) cp[(size_t)r * N] = acc[mi][ni][r];
    }
  }
}

// ---------------- K fake-quant: per-column stats over 2048 rows -----------
__global__ __launch_bounds__(256) void kquant(float* __restrict__ Kf) {
  __shared__ float s[2048];
  __shared__ float red[256];
  const int c = blockIdx.x, tid = threadIdx.x;
  float x[8];
#pragma unroll
  for (int i = 0; i < 8; i++) {
    x[i] = Kf[(size_t)(tid + i * 256) * KV_DIM + c];
    s[tid + i * 256] = x[i];
  }
  __syncthreads();
  for (int k = 2; k <= 2048; k <<= 1)
    for (int j = k >> 1; j > 0; j >>= 1) {
      for (int i = tid; i < 2048; i += 256) {
        int l = i ^ j;
        if (l > i) {
          float a = s[i], b2 = s[l];
          bool up = ((i & k) == 0);
          if ((a > b2) == up) { s[i] = b2; s[l] = a; }
        }
      }
      __syncthreads();
    }
  // n=2048: lower pos=1.0235, upper pos=2045.9765, lower-median idx 1023
  float lower = s[1]    + 0.0235f * (s[2]    - s[1]);
  float upper = s[2045] + 0.9765f * (s[2046] - s[2045]);
  float med   = s[1023];
  float mx = -__builtin_inff(), mn = __builtin_inff();
#pragma unroll
  for (int i = 0; i < 8; i++) {
    bool m = (x[i] <= lower) | (x[i] >= upper);
    float t = m ? med : x[i];
    mx = fmaxf(mx, t);
    mn = fminf(mn, t);
  }
  __syncthreads();
  red[tid] = mx; __syncthreads();
  for (int off = 128; off > 0; off >>= 1) {
    if (tid < off) red[tid] = fmaxf(red[tid], red[tid + off]);
    __syncthreads();
  }
  mx = red[0]; __syncthreads();
  red[tid] = mn; __syncthreads();
  for (int off = 128; off > 0; off >>= 1) {
    if (tid < off) red[tid] = fminf(red[tid], red[tid + off]);
    __syncthreads();
  }
  mn = red[0];
  float qx = 15.0f / (mx - mn);
  float offv = mn * qx;
#pragma unroll
  for (int i = 0; i < 8; i++) {
    bool m = (x[i] <= lower) | (x[i] >= upper);
    float inp = m ? 0.f : x[i];
    float q = rintf(qx * inp - offv);
    q = fminf(fmaxf(q, 0.f), 15.f);
    float deq = (q + offv) / qx;
    float o = m ? x[i] : deq;
    if (!__builtin_isfinite(o)) o = 0.f;
    Kf[(size_t)(tid + i * 256) * KV_DIM + c] = o;
  }
}

// ---------------- V fake-quant: per-row stats over 1024 cols --------------
__global__ __launch_bounds__(256) void vquant(float* __restrict__ Vf) {
  __shared__ float s[1024];
  __shared__ float red[256];
  const int rrow = blockIdx.x, tid = threadIdx.x;
  float x[4];
#pragma unroll
  for (int i = 0; i < 4; i++) {
    x[i] = Vf[(size_t)rrow * KV_DIM + tid + i * 256];
    s[tid + i * 256] = x[i];
  }
  __syncthreads();
  for (int k = 2; k <= 1024; k <<= 1)
    for (int j = k >> 1; j > 0; j >>= 1) {
      for (int i = tid; i < 1024; i += 256) {
        int l = i ^ j;
        if (l > i) {
          float a = s[i], b2 = s[l];
          bool up = ((i & k) == 0);
          if ((a > b2) == up) { s[i] = b2; s[l] = a; }
        }
      }
      __syncthreads();
    }
  // n=1024: lower pos=0.5115, upper pos=1022.4885, lower-median idx 511
  float lower = s[0]    + 0.5115f * (s[1]    - s[0]);
  float upper = s[1022] + 0.4885f * (s[1023] - s[1022]);
  float med   = s[511];
  float mx = -__builtin_inff(), mn = __builtin_inff();
#pragma unroll
  for (int i = 0; i < 4; i++) {
    bool m = (x[i] <= lower) | (x[i] >= upper);
    float t = m ? med : x[i];
    mx = fmaxf(mx, t);
    mn = fminf(mn, t);
  }
  __syncthreads();
  red[tid] = mx; __syncthreads();
  for (int off = 128; off > 0; off >>= 1) {
    if (tid < off) red[tid] = fmaxf(red[tid], red[tid + off]);
    __syncthreads();
  }
  mx = red[0]; __syncthreads();
  red[tid] = mn; __syncthreads();
  for (int off = 128; off > 0; off >>= 1) {
    if (tid < off) red[tid] = fminf(red[tid], red[tid + off]);
    __syncthreads();
  }
  mn = red[0];
  float qx = 15.0f / (mx - mn);
  float offv = mn * qx;
#pragma unroll
  for (int i = 0; i < 4; i++) {
    bool m = (x[i] <= lower) | (x[i] >= upper);
    float inp = m ? 0.f : x[i];
    float q = rintf(qx * inp - offv);
    q = fminf(fmaxf(q, 0.f), 15.f);
    float deq = (q + offv) / qx;
    float o = m ? x[i] : deq;
    if (!__builtin_isfinite(o)) o = 0.f;
    Vf[(size_t)rrow * KV_DIM + tid + i * 256] = o;
  }
}

// ---------------- RoPE Q: (B,S,H*D) fp32 -> (B,NH,S,D) bf16, prescaled ----
__global__ __launch_bounds__(256) void rope_q(const float* __restrict__ Q,
                                              const int* __restrict__ pos,
                                              unsigned short* __restrict__ qb) {
  int t = blockIdx.x * 256 + threadIdx.x;  // B*S*NH*64 threads
  int i = t & 63;
  int h = (t >> 6) & 31;
  int s = (t >> 11) & 1023;
  int b = t >> 21;
  int p = pos[b * S_LEN + s];
  float inv = expf(-9.210340371976184f * ((float)i * (1.0f / 64.0f)));
  float ang = (float)p * inv;
  float sn, cs;
  sincosf(ang, &sn, &cs);
  size_t base = ((size_t)(b * S_LEN + s)) * H_DIM + h * HDIM + i;
  float x1 = Q[base], x2 = Q[base + 64];
  const float sc = 0.08838834764831845f;  // 1/sqrt(128)
  size_t ob = (((size_t)(b * NHEADS + h)) * S_LEN + s) * HDIM + i;
  qb[ob]      = f2bf((x1 * cs - x2 * sn) * sc);
  qb[ob + 64] = f2bf((x2 * cs + x1 * sn) * sc);
}

// ---------------- RoPE K + pack V: -> (B,KVH,S,D) bf16 --------------------
__global__ __launch_bounds__(256) void rope_kv(const float* __restrict__ Kf,
                                               const float* __restrict__ Vf,
                                               const int* __restrict__ pos,
                                               unsigned short* __restrict__ kb,
                                               unsigned short* __restrict__ vb) {
  int t = blockIdx.x * 256 + threadIdx.x;  // B*S*KVH*64 threads
  int i = t & 63;
  int h = (t >> 6) & 7;
  int s = (t >> 9) & 1023;
  int b = t >> 19;
  int p = pos[b * S_LEN + s];
  float inv = expf(-9.210340371976184f * ((float)i * (1.0f / 64.0f)));
  float ang = (float)p * inv;
  float sn, cs;
  sincosf(ang, &sn, &cs);
  size_t base = ((size_t)(b * S_LEN + s)) * KV_DIM + h * HDIM + i;
  float k1 = Kf[base], k2 = Kf[base + 64];
  float v1 = Vf[base], v2 = Vf[base + 64];
  size_t ob = (((size_t)(b * KVHEADS + h)) * S_LEN + s) * HDIM + i;
  kb[ob]      = f2bf(k1 * cs - k2 * sn);
  kb[ob + 64] = f2bf(k2 * cs + k1 * sn);
  vb[ob]      = f2bf(v1);
  vb[ob + 64] = f2bf(v2);
}

// ---------------- Flash attention (causal, GQA) ---------------------------
// grid (S/64, B*NH); block 256 = 4 waves, wave w owns queries q0+w*16..+15
__global__ __launch_bounds__(256) void attn_fwd(const unsigned short* __restrict__ qb,
                                                const unsigned short* __restrict__ kb,
                                                const unsigned short* __restrict__ vb,
                                                unsigned short* __restrict__ ob) {
  __shared__ short Ks[64 * 136];   // keys row-major, padded
  __shared__ short Vs[128 * 72];   // V transposed: [d][key], padded
  __shared__ short Ps[4 * 16 * 72];// per-wave P tile
  const int tid = threadIdx.x;
  const int wid = tid >> 6;
  const int lane = tid & 63;
  const int ln = lane & 15;
  const int quad = lane >> 4;
  const int q0 = blockIdx.x * 64;
  const int bh = blockIdx.y;
  const int b = bh >> 5, h = bh & 31, hk = h >> 2;

  // Q fragments (A-layout): m=lane&15 -> query, k=quad*8+j
  const int sq = q0 + wid * 16 + ln;
  const unsigned short* qrow = qb + (((size_t)(b * NHEADS + h)) * S_LEN + sq) * HDIM;
  bf8 aq[4];
#pragma unroll
  for (int ks = 0; ks < 4; ks++) aq[ks] = *(const bf8*)(qrow + ks * 32 + quad * 8);

  f4 accO[8];
#pragma unroll
  for (int i = 0; i < 8; i++) accO[i] = (f4){0.f, 0.f, 0.f, 0.f};
  float mr[4] = {-__builtin_inff(), -__builtin_inff(), -__builtin_inff(), -__builtin_inff()};
  float lr[4] = {0.f, 0.f, 0.f, 0.f};

  const int ktiles = blockIdx.x + 1;
  for (int kt = 0; kt < ktiles; kt++) {
    const int k0 = kt * 64;
    __syncthreads();
    // stage K (row-major) and V (transposed)
    const unsigned short* kbp = kb + (((size_t)(b * KVHEADS + hk)) * S_LEN + k0) * HDIM;
    const unsigned short* vbp = vb + (((size_t)(b * KVHEADS + hk)) * S_LEN + k0) * HDIM;
#pragma unroll
    for (int cc = 0; cc < 4; cc++) {
      int c = tid + cc * 256;
      int r = c >> 4, c8 = c & 15;
      uint4 kv = *(const uint4*)(kbp + r * HDIM + c8 * 8);
      *(uint4*)&Ks[r * 136 + c8 * 8] = kv;
      uint4 vv = *(const uint4*)(vbp + r * HDIM + c8 * 8);
      const unsigned short* vp = (const unsigned short*)&vv;
#pragma unroll
      for (int j = 0; j < 8; j++) Vs[(c8 * 8 + j) * 72 + r] = (short)vp[j];
    }
    __syncthreads();

    // scores: 16 queries x 64 keys per wave
    f4 sc[4];
#pragma unroll
    for (int nt = 0; nt < 4; nt++) {
      sc[nt] = (f4){0.f, 0.f, 0.f, 0.f};
#pragma unroll
      for (int ks = 0; ks < 4; ks++) {
        bf8 bk = *(const bf8*)&Ks[(nt * 16 + ln) * 136 + ks * 32 + quad * 8];
        sc[nt] = __builtin_amdgcn_mfma_f32_16x16x32_bf16(aq[ks], bk, sc[nt], 0, 0, 0);
      }
    }
    // causal mask; C-layout: row=quad*4+r (query), col=ln (key)
#pragma unroll
    for (int r = 0; r < 4; r++) {
      int mq = q0 + wid * 16 + quad * 4 + r;
#pragma unroll
      for (int nt = 0; nt < 4; nt++) {
        int nk = k0 + nt * 16 + ln;
        if (nk > mq) sc[nt][r] = -1e30f;
      }
    }
    // online softmax
    float al[4];
#pragma unroll
    for (int r = 0; r < 4; r++) {
      float tm = fmaxf(fmaxf(sc[0][r], sc[1][r]), fmaxf(sc[2][r], sc[3][r]));
      tm = fmaxf(tm, __shfl_xor(tm, 1));
      tm = fmaxf(tm, __shfl_xor(tm, 2));
      tm = fmaxf(tm, __shfl_xor(tm, 4));
      tm = fmaxf(tm, __shfl_xor(tm, 8));
      float mnew = fmaxf(mr[r], tm);
      al[r] = __expf(mr[r] - mnew);
      mr[r] = mnew;
      float ls = 0.f;
#pragma unroll
      for (int nt = 0; nt < 4; nt++) {
        float pp = __expf(sc[nt][r] - mnew);
        sc[nt][r] = pp;
        ls += pp;
      }
      ls += __shfl_xor(ls, 1);
      ls += __shfl_xor(ls, 2);
      ls += __shfl_xor(ls, 4);
      ls += __shfl_xor(ls, 8);
      lr[r] = lr[r] * al[r] + ls;
    }
#pragma unroll
    for (int dt = 0; dt < 8; dt++)
#pragma unroll
      for (int r = 0; r < 4; r++) accO[dt][r] *= al[r];
    // P (C-layout) -> LDS -> reload in A-layout
#pragma unroll
    for (int r = 0; r < 4; r++)
#pragma unroll
      for (int nt = 0; nt < 4; nt++)
        Ps[wid * 1152 + (quad * 4 + r) * 72 + nt * 16 + ln] = (short)f2bf(sc[nt][r]);
    __syncthreads();
    bf8 ap[2];
#pragma unroll
    for (int k2 = 0; k2 < 2; k2++)
      ap[k2] = *(const bf8*)&Ps[wid * 1152 + ln * 72 + k2 * 32 + quad * 8];
    // O += P @ V
#pragma unroll
    for (int dt = 0; dt < 8; dt++)
#pragma unroll
      for (int k2 = 0; k2 < 2; k2++) {
        bf8 bv = *(const bf8*)&Vs[(dt * 16 + ln) * 72 + k2 * 32 + quad * 8];
        accO[dt] = __builtin_amdgcn_mfma_f32_16x16x32_bf16(ap[k2], bv, accO[dt], 0, 0, 0);
      }
  }
  // epilogue: write (B,S,NH*D) bf16
#pragma unroll
  for (int r = 0; r < 4; r++) {
    float invl = 1.0f / lr[r];
    int so = q0 + wid * 16 + quad * 4 + r;
    size_t obase = ((size_t)(b * S_LEN + so)) * H_DIM + h * HDIM;
#pragma unroll
    for (int dt = 0; dt < 8; dt++)
      ob[obase + dt * 16 + ln] = f2bf(accO[dt][r] * invl);
  }
}

extern "C" void kernel_launch(void* const* d_in, const int* in_sizes, int n_in,
                              void* d_out, int out_size, void* d_ws, size_t ws_size,
                              hipStream_t stream) {
  const float* hidden = (const float*)d_in[0];
  const float* Wq = (const float*)d_in[1];
  const float* Wk = (const float*)d_in[2];
  const float* Wv = (const float*)d_in[3];
  const float* Wo = (const float*)d_in[4];
  const int* pos = (const int*)d_in[5];
  float* outp = (float*)d_out;

  char* ws = (char*)d_ws;
  float* Qf = (float*)ws;                   ws += (size_t)BS_C * H_DIM * 4;   // 33.6 MB
  float* Kf = (float*)ws;                   ws += (size_t)BS_C * KV_DIM * 4;  // 8.4 MB
  float* Vf = (float*)ws;                   ws += (size_t)BS_C * KV_DIM * 4;  // 8.4 MB
  unsigned short* qb = (unsigned short*)ws; ws += (size_t)BS_C * H_DIM * 2;   // 16.8 MB
  unsigned short* kb = (unsigned short*)ws; ws += (size_t)BS_C * KV_DIM * 2;  // 4.2 MB
  unsigned short* vb = (unsigned short*)ws; ws += (size_t)BS_C * KV_DIM * 2;  // 4.2 MB
  unsigned short* ab = (unsigned short*)ws;                                   // 16.8 MB

  // projections
  gemm_bt<false, false><<<dim3(32, 16), 256, 0, stream>>>((const void*)hidden, Wq, Qf, 2048, 4096, 4096);
  gemm_bt<true,  false><<<dim3(8, 16),  256, 0, stream>>>((const void*)hidden, Wk, Kf, 2048, 1024, 4096);
  gemm_bt<true,  false><<<dim3(8, 16),  256, 0, stream>>>((const void*)hidden, Wv, Vf, 2048, 1024, 4096);
  // fake-quant (in place, exact order statistics via LDS bitonic sort)
  kquant<<<1024, 256, 0, stream>>>(Kf);
  vquant<<<2048, 256, 0, stream>>>(Vf);
  // RoPE + layout + bf16 pack
  rope_q<<<16384, 256, 0, stream>>>(Qf, pos, qb);
  rope_kv<<<4096, 256, 0, stream>>>(Kf, Vf, pos, kb, vb);
  // causal GQA flash attention
  attn_fwd<<<dim3(16, 64), 256, 0, stream>>>(qb, kb, vb, ab);
  // output projection
  gemm_bt<false, true><<<dim3(32, 16), 256, 0, stream>>>((const void*)ab, Wo, outp, 2048, 4096, 4096);
}

// Round 2
// 930.532 us; speedup vs baseline: 1.4647x; 1.4647x over previous
//
#include <hip/hip_runtime.h>

#define S_LEN 1024
#define B_SZ 2
#define H_DIM 4096
#define NHEADS 32
#define KVHEADS 8
#define HDIM 128
#define KV_DIM 1024
#define BS_C 2048

typedef short bf8 __attribute__((ext_vector_type(8)));
typedef float f4 __attribute__((ext_vector_type(4)));
typedef unsigned short ushort_t;

static __device__ __forceinline__ unsigned short f2bf(float x) {
  unsigned int u = __float_as_uint(x);
  u += 0x7fffu + ((u >> 16) & 1u);
  return (unsigned short)(u >> 16);
}
static __device__ __forceinline__ float bf2f(unsigned short h) {
  return __uint_as_float(((unsigned int)h) << 16);
}

// async global->LDS, 16B per lane. LDS dest must be wave-uniform base + lane*16.
static __device__ __forceinline__ void gl2lds16(const void* g, void* l) {
  __builtin_amdgcn_global_load_lds(
      (const __attribute__((address_space(1))) unsigned int*)(unsigned long long)(uintptr_t)g,
      (__attribute__((address_space(3))) unsigned int*)(unsigned int)(uintptr_t)l,
      16, 0, 0);
}

// ---------------- fp32 -> bf16 hi(+lo) conversion ------------------------
__global__ __launch_bounds__(256) void cvt_split(const float* __restrict__ x,
                                                 ushort_t* __restrict__ hi,
                                                 ushort_t* __restrict__ lo, int n4) {
  int i = blockIdx.x * 256 + threadIdx.x;
  if (i >= n4) return;
  float4 v = ((const float4*)x)[i];
  unsigned short h0 = f2bf(v.x), h1 = f2bf(v.y), h2 = f2bf(v.z), h3 = f2bf(v.w);
  unsigned short l0 = f2bf(v.x - bf2f(h0)), l1 = f2bf(v.y - bf2f(h1));
  unsigned short l2 = f2bf(v.z - bf2f(h2)), l3 = f2bf(v.w - bf2f(h3));
  uint2 hp; hp.x = (unsigned)h0 | ((unsigned)h1 << 16); hp.y = (unsigned)h2 | ((unsigned)h3 << 16);
  uint2 lp; lp.x = (unsigned)l0 | ((unsigned)l1 << 16); lp.y = (unsigned)l2 | ((unsigned)l3 << 16);
  ((uint2*)hi)[i] = hp;
  ((uint2*)lo)[i] = lp;
}

__global__ __launch_bounds__(256) void cvt_hi(const float* __restrict__ x,
                                              ushort_t* __restrict__ hi, int n4) {
  int i = blockIdx.x * 256 + threadIdx.x;
  if (i >= n4) return;
  float4 v = ((const float4*)x)[i];
  unsigned short h0 = f2bf(v.x), h1 = f2bf(v.y), h2 = f2bf(v.z), h3 = f2bf(v.w);
  uint2 hp; hp.x = (unsigned)h0 | ((unsigned)h1 << 16); hp.y = (unsigned)h2 | ((unsigned)h3 << 16);
  ((uint2*)hi)[i] = hp;
}

// ---------------- GEMM: C[M,N] = A[M,K] @ B[N,K]^T, bf16 in, m97 structure
// SPLIT: hi/lo 3-pass for ~fp32 accuracy. OUT16: write bf16 instead of fp32.
template<bool SPLIT, bool OUT16>
__global__ __launch_bounds__(256) void gemm16(const ushort_t* __restrict__ Ahg,
                                              const ushort_t* __restrict__ Alg,
                                              const ushort_t* __restrict__ Bhg,
                                              const ushort_t* __restrict__ Blg,
                                              void* __restrict__ Cp,
                                              int M, int N, int K) {
  __shared__ short Ah[128 * 32];
  __shared__ short Bh[128 * 32];
  __shared__ short Al[SPLIT ? 128 * 32 : 8];
  __shared__ short Bl[SPLIT ? 128 * 32 : 8];

  const int tid = threadIdx.x;
  const int wid = tid >> 6;
  const int lane = tid & 63;
  const int ln = lane & 15;
  const int quad = lane >> 4;
  const int wx = wid & 1, wy = wid >> 1;
  const int m0 = blockIdx.y * 128, n0 = blockIdx.x * 128;
  const int sr = tid >> 2, sc = (tid & 3) * 8;  // staging: row tid/4, col (tid&3)*8

  const ushort_t* ap0 = Ahg + (size_t)(m0 + sr) * K + sc;
  const ushort_t* bp0 = Bhg + (size_t)(n0 + sr) * K + sc;
  const ushort_t* ap1 = SPLIT ? Alg + (size_t)(m0 + sr) * K + sc : nullptr;
  const ushort_t* bp1 = SPLIT ? Blg + (size_t)(n0 + sr) * K + sc : nullptr;
  const size_t rs = (size_t)64 * K;

  f4 acc[4][4];
#pragma unroll
  for (int i = 0; i < 4; i++)
#pragma unroll
    for (int j = 0; j < 4; j++) acc[i][j] = (f4){0.f, 0.f, 0.f, 0.f};

  for (int kk = 0; kk < K; kk += 32) {
    gl2lds16(ap0 + kk,      &Ah[tid * 8]);
    gl2lds16(ap0 + kk + rs, &Ah[2048 + tid * 8]);
    gl2lds16(bp0 + kk,      &Bh[tid * 8]);
    gl2lds16(bp0 + kk + rs, &Bh[2048 + tid * 8]);
    if (SPLIT) {
      gl2lds16(ap1 + kk,      &Al[tid * 8]);
      gl2lds16(ap1 + kk + rs, &Al[2048 + tid * 8]);
      gl2lds16(bp1 + kk,      &Bl[tid * 8]);
      gl2lds16(bp1 + kk + rs, &Bl[2048 + tid * 8]);
    }
    __syncthreads();  // drains vmcnt(0): LDS tiles ready

    bf8 af[4], bfr[4], afl[4], bfl[4];
#pragma unroll
    for (int mi = 0; mi < 4; mi++)
      af[mi] = *(const bf8*)&Ah[(wy * 64 + mi * 16 + ln) * 32 + quad * 8];
#pragma unroll
    for (int ni = 0; ni < 4; ni++)
      bfr[ni] = *(const bf8*)&Bh[(wx * 64 + ni * 16 + ln) * 32 + quad * 8];
    if (SPLIT) {
#pragma unroll
      for (int mi = 0; mi < 4; mi++)
        afl[mi] = *(const bf8*)&Al[(wy * 64 + mi * 16 + ln) * 32 + quad * 8];
#pragma unroll
      for (int ni = 0; ni < 4; ni++)
        bfl[ni] = *(const bf8*)&Bl[(wx * 64 + ni * 16 + ln) * 32 + quad * 8];
    }
    __syncthreads();  // frags in regs; next staging may overlap MFMA

#pragma unroll
    for (int mi = 0; mi < 4; mi++)
#pragma unroll
      for (int ni = 0; ni < 4; ni++) {
        acc[mi][ni] = __builtin_amdgcn_mfma_f32_16x16x32_bf16(af[mi], bfr[ni], acc[mi][ni], 0, 0, 0);
        if (SPLIT) {
          acc[mi][ni] = __builtin_amdgcn_mfma_f32_16x16x32_bf16(af[mi], bfl[ni], acc[mi][ni], 0, 0, 0);
          acc[mi][ni] = __builtin_amdgcn_mfma_f32_16x16x32_bf16(afl[mi], bfr[ni], acc[mi][ni], 0, 0, 0);
        }
      }
  }

  // epilogue: C/D layout col=lane&15, row=quad*4+reg
#pragma unroll
  for (int mi = 0; mi < 4; mi++) {
    int m = m0 + wy * 64 + mi * 16 + quad * 4;
#pragma unroll
    for (int ni = 0; ni < 4; ni++) {
      int n = n0 + wx * 64 + ni * 16 + ln;
      if (OUT16) {
        ushort_t* cp = (ushort_t*)Cp + (size_t)m * N + n;
#pragma unroll
        for (int r = 0; r < 4; r++) cp[(size_t)r * N] = f2bf(acc[mi][ni][r]);
      } else {
        float* cp = (float*)Cp + (size_t)m * N + n;
#pragma unroll
        for (int r = 0; r < 4; r++) cp[(size_t)r * N] = acc[mi][ni][r];
      }
    }
  }
}

// ---------------- K fake-quant: per-column stats over 2048 rows -----------
// KV combined layout: row-major (2048 rows, 2048 cols); K = cols 0..1023
__global__ __launch_bounds__(256) void kquant(float* __restrict__ KV) {
  __shared__ float s[2048];
  __shared__ float red[256];
  const int c = blockIdx.x, tid = threadIdx.x;
  float x[8];
#pragma unroll
  for (int i = 0; i < 8; i++) {
    x[i] = KV[(size_t)(tid + i * 256) * 2048 + c];
    s[tid + i * 256] = x[i];
  }
  __syncthreads();
  for (int k = 2; k <= 2048; k <<= 1)
    for (int j = k >> 1; j > 0; j >>= 1) {
      for (int i = tid; i < 2048; i += 256) {
        int l = i ^ j;
        if (l > i) {
          float a = s[i], b2 = s[l];
          bool up = ((i & k) == 0);
          if ((a > b2) == up) { s[i] = b2; s[l] = a; }
        }
      }
      __syncthreads();
    }
  float lower = s[1]    + 0.0235f * (s[2]    - s[1]);
  float upper = s[2045] + 0.9765f * (s[2046] - s[2045]);
  float med   = s[1023];
  float mx = -__builtin_inff(), mn = __builtin_inff();
#pragma unroll
  for (int i = 0; i < 8; i++) {
    bool m = (x[i] <= lower) | (x[i] >= upper);
    float t = m ? med : x[i];
    mx = fmaxf(mx, t);
    mn = fminf(mn, t);
  }
  __syncthreads();
  red[tid] = mx; __syncthreads();
  for (int off = 128; off > 0; off >>= 1) {
    if (tid < off) red[tid] = fmaxf(red[tid], red[tid + off]);
    __syncthreads();
  }
  mx = red[0]; __syncthreads();
  red[tid] = mn; __syncthreads();
  for (int off = 128; off > 0; off >>= 1) {
    if (tid < off) red[tid] = fminf(red[tid], red[tid + off]);
    __syncthreads();
  }
  mn = red[0];
  float qx = 15.0f / (mx - mn);
  float offv = mn * qx;
#pragma unroll
  for (int i = 0; i < 8; i++) {
    bool m = (x[i] <= lower) | (x[i] >= upper);
    float inp = m ? 0.f : x[i];
    float q = rintf(qx * inp - offv);
    q = fminf(fmaxf(q, 0.f), 15.f);
    float deq = (q + offv) / qx;
    float o = m ? x[i] : deq;
    if (!__builtin_isfinite(o)) o = 0.f;
    KV[(size_t)(tid + i * 256) * 2048 + c] = o;
  }
}

// ---------------- V fake-quant: per-row stats; V = cols 1024..2047 --------
__global__ __launch_bounds__(256) void vquant(float* __restrict__ KV) {
  __shared__ float s[1024];
  __shared__ float red[256];
  const int rrow = blockIdx.x, tid = threadIdx.x;
  float x[4];
#pragma unroll
  for (int i = 0; i < 4; i++) {
    x[i] = KV[(size_t)rrow * 2048 + 1024 + tid + i * 256];
    s[tid + i * 256] = x[i];
  }
  __syncthreads();
  for (int k = 2; k <= 1024; k <<= 1)
    for (int j = k >> 1; j > 0; j >>= 1) {
      for (int i = tid; i < 1024; i += 256) {
        int l = i ^ j;
        if (l > i) {
          float a = s[i], b2 = s[l];
          bool up = ((i & k) == 0);
          if ((a > b2) == up) { s[i] = b2; s[l] = a; }
        }
      }
      __syncthreads();
    }
  float lower = s[0]    + 0.5115f * (s[1]    - s[0]);
  float upper = s[1022] + 0.4885f * (s[1023] - s[1022]);
  float med   = s[511];
  float mx = -__builtin_inff(), mn = __builtin_inff();
#pragma unroll
  for (int i = 0; i < 4; i++) {
    bool m = (x[i] <= lower) | (x[i] >= upper);
    float t = m ? med : x[i];
    mx = fmaxf(mx, t);
    mn = fminf(mn, t);
  }
  __syncthreads();
  red[tid] = mx; __syncthreads();
  for (int off = 128; off > 0; off >>= 1) {
    if (tid < off) red[tid] = fmaxf(red[tid], red[tid + off]);
    __syncthreads();
  }
  mx = red[0]; __syncthreads();
  red[tid] = mn; __syncthreads();
  for (int off = 128; off > 0; off >>= 1) {
    if (tid < off) red[tid] = fminf(red[tid], red[tid + off]);
    __syncthreads();
  }
  mn = red[0];
  float qx = 15.0f / (mx - mn);
  float offv = mn * qx;
#pragma unroll
  for (int i = 0; i < 4; i++) {
    bool m = (x[i] <= lower) | (x[i] >= upper);
    float inp = m ? 0.f : x[i];
    float q = rintf(qx * inp - offv);
    q = fminf(fmaxf(q, 0.f), 15.f);
    float deq = (q + offv) / qx;
    float o = m ? x[i] : deq;
    if (!__builtin_isfinite(o)) o = 0.f;
    KV[(size_t)rrow * 2048 + 1024 + tid + i * 256] = o;
  }
}

// ---------------- RoPE Q: (B,S,NH*D) bf16 -> (B,NH,S,D) bf16, prescaled ---
__global__ __launch_bounds__(256) void rope_q(const ushort_t* __restrict__ Q,
                                              const int* __restrict__ pos,
                                              ushort_t* __restrict__ qb) {
  int t = blockIdx.x * 256 + threadIdx.x;
  int i = t & 63;
  int h = (t >> 6) & 31;
  int s = (t >> 11) & 1023;
  int b = t >> 21;
  int p = pos[b * S_LEN + s];
  float inv = expf(-9.210340371976184f * ((float)i * (1.0f / 64.0f)));
  float ang = (float)p * inv;
  float sn, cs;
  sincosf(ang, &sn, &cs);
  size_t base = ((size_t)(b * S_LEN + s)) * H_DIM + h * HDIM + i;
  float x1 = bf2f(Q[base]), x2 = bf2f(Q[base + 64]);
  const float sc = 0.08838834764831845f;  // 1/sqrt(128)
  size_t ob = (((size_t)(b * NHEADS + h)) * S_LEN + s) * HDIM + i;
  qb[ob]      = f2bf((x1 * cs - x2 * sn) * sc);
  qb[ob + 64] = f2bf((x2 * cs + x1 * sn) * sc);
}

// ---------------- RoPE K + pack V from combined KV fp32 -------------------
__global__ __launch_bounds__(256) void rope_kv(const float* __restrict__ KV,
                                               const int* __restrict__ pos,
                                               ushort_t* __restrict__ kb,
                                               ushort_t* __restrict__ vb) {
  int t = blockIdx.x * 256 + threadIdx.x;
  int i = t & 63;
  int h = (t >> 6) & 7;
  int s = (t >> 9) & 1023;
  int b = t >> 19;
  int p = pos[b * S_LEN + s];
  float inv = expf(-9.210340371976184f * ((float)i * (1.0f / 64.0f)));
  float ang = (float)p * inv;
  float sn, cs;
  sincosf(ang, &sn, &cs);
  size_t base = ((size_t)(b * S_LEN + s)) * 2048 + h * HDIM + i;
  float k1 = KV[base], k2 = KV[base + 64];
  float v1 = KV[base + 1024], v2 = KV[base + 1024 + 64];
  size_t ob = (((size_t)(b * KVHEADS + h)) * S_LEN + s) * HDIM + i;
  kb[ob]      = f2bf(k1 * cs - k2 * sn);
  kb[ob + 64] = f2bf(k2 * cs + k1 * sn);
  vb[ob]      = f2bf(v1);
  vb[ob + 64] = f2bf(v2);
}

// ---------------- Flash attention (causal, GQA) ---------------------------
__global__ __launch_bounds__(256) void attn_fwd(const ushort_t* __restrict__ qb,
                                                const ushort_t* __restrict__ kb,
                                                const ushort_t* __restrict__ vb,
                                                ushort_t* __restrict__ ob) {
  __shared__ short Ks[64 * 136];
  __shared__ short Vs[128 * 72];
  __shared__ short Ps[4 * 16 * 72];
  const int tid = threadIdx.x;
  const int wid = tid >> 6;
  const int lane = tid & 63;
  const int ln = lane & 15;
  const int quad = lane >> 4;
  const int q0 = blockIdx.x * 64;
  const int bh = blockIdx.y;
  const int b = bh >> 5, h = bh & 31, hk = h >> 2;

  const int sq = q0 + wid * 16 + ln;
  const ushort_t* qrow = qb + (((size_t)(b * NHEADS + h)) * S_LEN + sq) * HDIM;
  bf8 aq[4];
#pragma unroll
  for (int ks = 0; ks < 4; ks++) aq[ks] = *(const bf8*)(qrow + ks * 32 + quad * 8);

  f4 accO[8];
#pragma unroll
  for (int i = 0; i < 8; i++) accO[i] = (f4){0.f, 0.f, 0.f, 0.f};
  float mr[4] = {-__builtin_inff(), -__builtin_inff(), -__builtin_inff(), -__builtin_inff()};
  float lr[4] = {0.f, 0.f, 0.f, 0.f};

  const int ktiles = blockIdx.x + 1;
  for (int kt = 0; kt < ktiles; kt++) {
    const int k0 = kt * 64;
    __syncthreads();
    const ushort_t* kbp = kb + (((size_t)(b * KVHEADS + hk)) * S_LEN + k0) * HDIM;
    const ushort_t* vbp = vb + (((size_t)(b * KVHEADS + hk)) * S_LEN + k0) * HDIM;
#pragma unroll
    for (int cc = 0; cc < 4; cc++) {
      int c = tid + cc * 256;
      int r = c >> 4, c8 = c & 15;
      uint4 kv = *(const uint4*)(kbp + r * HDIM + c8 * 8);
      *(uint4*)&Ks[r * 136 + c8 * 8] = kv;
      uint4 vv = *(const uint4*)(vbp + r * HDIM + c8 * 8);
      const ushort_t* vp = (const ushort_t*)&vv;
#pragma unroll
      for (int j = 0; j < 8; j++) Vs[(c8 * 8 + j) * 72 + r] = (short)vp[j];
    }
    __syncthreads();

    f4 sc[4];
#pragma unroll
    for (int nt = 0; nt < 4; nt++) {
      sc[nt] = (f4){0.f, 0.f, 0.f, 0.f};
#pragma unroll
      for (int ks = 0; ks < 4; ks++) {
        bf8 bk = *(const bf8*)&Ks[(nt * 16 + ln) * 136 + ks * 32 + quad * 8];
        sc[nt] = __builtin_amdgcn_mfma_f32_16x16x32_bf16(aq[ks], bk, sc[nt], 0, 0, 0);
      }
    }
#pragma unroll
    for (int r = 0; r < 4; r++) {
      int mq = q0 + wid * 16 + quad * 4 + r;
#pragma unroll
      for (int nt = 0; nt < 4; nt++) {
        int nk = k0 + nt * 16 + ln;
        if (nk > mq) sc[nt][r] = -1e30f;
      }
    }
    float al[4];
#pragma unroll
    for (int r = 0; r < 4; r++) {
      float tm = fmaxf(fmaxf(sc[0][r], sc[1][r]), fmaxf(sc[2][r], sc[3][r]));
      tm = fmaxf(tm, __shfl_xor(tm, 1));
      tm = fmaxf(tm, __shfl_xor(tm, 2));
      tm = fmaxf(tm, __shfl_xor(tm, 4));
      tm = fmaxf(tm, __shfl_xor(tm, 8));
      float mnew = fmaxf(mr[r], tm);
      al[r] = __expf(mr[r] - mnew);
      mr[r] = mnew;
      float ls = 0.f;
#pragma unroll
      for (int nt = 0; nt < 4; nt++) {
        float pp = __expf(sc[nt][r] - mnew);
        sc[nt][r] = pp;
        ls += pp;
      }
      ls += __shfl_xor(ls, 1);
      ls += __shfl_xor(ls, 2);
      ls += __shfl_xor(ls, 4);
      ls += __shfl_xor(ls, 8);
      lr[r] = lr[r] * al[r] + ls;
    }
#pragma unroll
    for (int dt = 0; dt < 8; dt++)
#pragma unroll
      for (int r = 0; r < 4; r++) accO[dt][r] *= al[r];
#pragma unroll
    for (int r = 0; r < 4; r++)
#pragma unroll
      for (int nt = 0; nt < 4; nt++)
        Ps[wid * 1152 + (quad * 4 + r) * 72 + nt * 16 + ln] = (short)f2bf(sc[nt][r]);
    __syncthreads();
    bf8 ap[2];
#pragma unroll
    for (int k2 = 0; k2 < 2; k2++)
      ap[k2] = *(const bf8*)&Ps[wid * 1152 + ln * 72 + k2 * 32 + quad * 8];
#pragma unroll
    for (int dt = 0; dt < 8; dt++)
#pragma unroll
      for (int k2 = 0; k2 < 2; k2++) {
        bf8 bv = *(const bf8*)&Vs[(dt * 16 + ln) * 72 + k2 * 32 + quad * 8];
        accO[dt] = __builtin_amdgcn_mfma_f32_16x16x32_bf16(ap[k2], bv, accO[dt], 0, 0, 0);
      }
  }
#pragma unroll
  for (int r = 0; r < 4; r++) {
    float invl = 1.0f / lr[r];
    int so = q0 + wid * 16 + quad * 4 + r;
    size_t obase = ((size_t)(b * S_LEN + so)) * H_DIM + h * HDIM;
#pragma unroll
    for (int dt = 0; dt < 8; dt++)
      ob[obase + dt * 16 + ln] = f2bf(accO[dt][r] * invl);
  }
}

extern "C" void kernel_launch(void* const* d_in, const int* in_sizes, int n_in,
                              void* d_out, int out_size, void* d_ws, size_t ws_size,
                              hipStream_t stream) {
  const float* hidden = (const float*)d_in[0];
  const float* Wq = (const float*)d_in[1];
  const float* Wk = (const float*)d_in[2];
  const float* Wv = (const float*)d_in[3];
  const float* Wo = (const float*)d_in[4];
  const int* pos = (const int*)d_in[5];
  float* outp = (float*)d_out;

  // workspace layout with lifetime-based reuse (total ~134 MB)
  char* ws = (char*)d_ws;
  ushort_t* wqh  = (ushort_t*)ws; ws += (size_t)4096 * 4096 * 2;  // Wq-hi, later Wo-hi
  ushort_t* hh   = (ushort_t*)ws; ws += (size_t)2048 * 4096 * 2;  // hidden hi; later ab
  ushort_t* hl   = (ushort_t*)ws; ws += (size_t)2048 * 4096 * 2;  // hidden lo
  ushort_t* kvwh = (ushort_t*)ws; ws += (size_t)2048 * 4096 * 2;  // [Wk;Wv] hi; later qb
  ushort_t* kvwl = (ushort_t*)ws; ws += (size_t)2048 * 4096 * 2;  // [Wk;Wv] lo; later kb+vb
  ushort_t* Qf16 = (ushort_t*)ws; ws += (size_t)2048 * 4096 * 2;  // Q proj out (B,S,NH*D)
  float*    KVf  = (float*)ws;                                    // KV proj out (2048,2048) fp32

  ushort_t* qb = kvwh;                         // (B,NH,S,D)  16.78 MB
  ushort_t* kb = kvwl;                         // (B,KVH,S,D)  4.19 MB
  ushort_t* vb = kvwl + (size_t)2 * KVHEADS * S_LEN * HDIM;
  ushort_t* ab = hh;                           // attn out (B,S,NH*D)

  // conversions
  cvt_split<<<8192, 256, 0, stream>>>(hidden, hh, hl, 2048 * 4096 / 4);
  cvt_hi<<<16384, 256, 0, stream>>>(Wq, wqh, 4096 * 4096 / 4);
  cvt_split<<<4096, 256, 0, stream>>>(Wk, kvwh, kvwl, 1024 * 4096 / 4);
  cvt_split<<<4096, 256, 0, stream>>>(Wv, kvwh + (size_t)1024 * 4096, kvwl + (size_t)1024 * 4096, 1024 * 4096 / 4);

  // projections
  gemm16<false, true><<<dim3(32, 16), 256, 0, stream>>>(hh, nullptr, wqh, nullptr, (void*)Qf16, 2048, 4096, 4096);
  gemm16<true, false><<<dim3(16, 16), 256, 0, stream>>>(hh, hl, kvwh, kvwl, (void*)KVf, 2048, 2048, 4096);

  // fake-quant in place on combined KV
  kquant<<<1024, 256, 0, stream>>>(KVf);
  vquant<<<2048, 256, 0, stream>>>(KVf);

  // RoPE + layout + bf16 pack (qb/kb/vb overlay dead weight buffers)
  rope_q<<<16384, 256, 0, stream>>>(Qf16, pos, qb);
  rope_kv<<<4096, 256, 0, stream>>>(KVf, pos, kb, vb);

  // Wo conversion into wqh (Wq-hi dead after Q GEMM)
  cvt_hi<<<16384, 256, 0, stream>>>(Wo, wqh, 4096 * 4096 / 4);

  // attention
  attn_fwd<<<dim3(16, 64), 256, 0, stream>>>(qb, kb, vb, ab);

  // output projection
  gemm16<false, false><<<dim3(32, 16), 256, 0, stream>>>(ab, nullptr, wqh, nullptr, (void*)outp, 2048, 4096, 4096);
}

// Round 3
// 850.935 us; speedup vs baseline: 1.6017x; 1.0935x over previous
//
#include <hip/hip_runtime.h>

#define S_LEN 1024
#define B_SZ 2
#define H_DIM 4096
#define NHEADS 32
#define KVHEADS 8
#define HDIM 128
#define KV_DIM 1024
#define BS_C 2048

typedef short bf8 __attribute__((ext_vector_type(8)));
typedef float f4 __attribute__((ext_vector_type(4)));
typedef unsigned short ushort_t;

static __device__ __forceinline__ unsigned short f2bf(float x) {
  unsigned int u = __float_as_uint(x);
  u += 0x7fffu + ((u >> 16) & 1u);
  return (unsigned short)(u >> 16);
}
static __device__ __forceinline__ float bf2f(unsigned short h) {
  return __uint_as_float(((unsigned int)h) << 16);
}

// async global->LDS, 16B per lane. LDS dest must be wave-uniform base + lane*16.
static __device__ __forceinline__ void gl2lds16(const void* g, void* l) {
  __builtin_amdgcn_global_load_lds(
      (const __attribute__((address_space(1))) unsigned int*)(unsigned long long)(uintptr_t)g,
      (__attribute__((address_space(3))) unsigned int*)(unsigned int)(uintptr_t)l,
      16, 0, 0);
}

// ---------------- fp32 -> bf16 hi(+lo) conversion ------------------------
__global__ __launch_bounds__(256) void cvt_split(const float* __restrict__ x,
                                                 ushort_t* __restrict__ hi,
                                                 ushort_t* __restrict__ lo, int n4) {
  int i = blockIdx.x * 256 + threadIdx.x;
  if (i >= n4) return;
  float4 v = ((const float4*)x)[i];
  unsigned short h0 = f2bf(v.x), h1 = f2bf(v.y), h2 = f2bf(v.z), h3 = f2bf(v.w);
  unsigned short l0 = f2bf(v.x - bf2f(h0)), l1 = f2bf(v.y - bf2f(h1));
  unsigned short l2 = f2bf(v.z - bf2f(h2)), l3 = f2bf(v.w - bf2f(h3));
  uint2 hp; hp.x = (unsigned)h0 | ((unsigned)h1 << 16); hp.y = (unsigned)h2 | ((unsigned)h3 << 16);
  uint2 lp; lp.x = (unsigned)l0 | ((unsigned)l1 << 16); lp.y = (unsigned)l2 | ((unsigned)l3 << 16);
  ((uint2*)hi)[i] = hp;
  ((uint2*)lo)[i] = lp;
}

__global__ __launch_bounds__(256) void cvt_hi(const float* __restrict__ x,
                                              ushort_t* __restrict__ hi, int n4) {
  int i = blockIdx.x * 256 + threadIdx.x;
  if (i >= n4) return;
  float4 v = ((const float4*)x)[i];
  unsigned short h0 = f2bf(v.x), h1 = f2bf(v.y), h2 = f2bf(v.z), h3 = f2bf(v.w);
  uint2 hp; hp.x = (unsigned)h0 | ((unsigned)h1 << 16); hp.y = (unsigned)h2 | ((unsigned)h3 << 16);
  ((uint2*)hi)[i] = hp;
}

// ---------------- GEMM: C[M,N] = A[M,K] @ B[N,K]^T, bf16 in, m97 structure
template<bool SPLIT, bool OUT16>
__global__ __launch_bounds__(256) void gemm16(const ushort_t* __restrict__ Ahg,
                                              const ushort_t* __restrict__ Alg,
                                              const ushort_t* __restrict__ Bhg,
                                              const ushort_t* __restrict__ Blg,
                                              void* __restrict__ Cp,
                                              int M, int N, int K) {
  __shared__ short Ah[128 * 32];
  __shared__ short Bh[128 * 32];
  __shared__ short Al[SPLIT ? 128 * 32 : 8];
  __shared__ short Bl[SPLIT ? 128 * 32 : 8];

  const int tid = threadIdx.x;
  const int wid = tid >> 6;
  const int lane = tid & 63;
  const int ln = lane & 15;
  const int quad = lane >> 4;
  const int wx = wid & 1, wy = wid >> 1;
  const int m0 = blockIdx.y * 128, n0 = blockIdx.x * 128;
  const int sr = tid >> 2, sc = (tid & 3) * 8;

  const ushort_t* ap0 = Ahg + (size_t)(m0 + sr) * K + sc;
  const ushort_t* bp0 = Bhg + (size_t)(n0 + sr) * K + sc;
  const ushort_t* ap1 = SPLIT ? Alg + (size_t)(m0 + sr) * K + sc : nullptr;
  const ushort_t* bp1 = SPLIT ? Blg + (size_t)(n0 + sr) * K + sc : nullptr;
  const size_t rs = (size_t)64 * K;

  f4 acc[4][4];
#pragma unroll
  for (int i = 0; i < 4; i++)
#pragma unroll
    for (int j = 0; j < 4; j++) acc[i][j] = (f4){0.f, 0.f, 0.f, 0.f};

  for (int kk = 0; kk < K; kk += 32) {
    gl2lds16(ap0 + kk,      &Ah[tid * 8]);
    gl2lds16(ap0 + kk + rs, &Ah[2048 + tid * 8]);
    gl2lds16(bp0 + kk,      &Bh[tid * 8]);
    gl2lds16(bp0 + kk + rs, &Bh[2048 + tid * 8]);
    if (SPLIT) {
      gl2lds16(ap1 + kk,      &Al[tid * 8]);
      gl2lds16(ap1 + kk + rs, &Al[2048 + tid * 8]);
      gl2lds16(bp1 + kk,      &Bl[tid * 8]);
      gl2lds16(bp1 + kk + rs, &Bl[2048 + tid * 8]);
    }
    __syncthreads();

    bf8 af[4], bfr[4], afl[4], bfl[4];
#pragma unroll
    for (int mi = 0; mi < 4; mi++)
      af[mi] = *(const bf8*)&Ah[(wy * 64 + mi * 16 + ln) * 32 + quad * 8];
#pragma unroll
    for (int ni = 0; ni < 4; ni++)
      bfr[ni] = *(const bf8*)&Bh[(wx * 64 + ni * 16 + ln) * 32 + quad * 8];
    if (SPLIT) {
#pragma unroll
      for (int mi = 0; mi < 4; mi++)
        afl[mi] = *(const bf8*)&Al[(wy * 64 + mi * 16 + ln) * 32 + quad * 8];
#pragma unroll
      for (int ni = 0; ni < 4; ni++)
        bfl[ni] = *(const bf8*)&Bl[(wx * 64 + ni * 16 + ln) * 32 + quad * 8];
    }
    __syncthreads();

#pragma unroll
    for (int mi = 0; mi < 4; mi++)
#pragma unroll
      for (int ni = 0; ni < 4; ni++) {
        acc[mi][ni] = __builtin_amdgcn_mfma_f32_16x16x32_bf16(af[mi], bfr[ni], acc[mi][ni], 0, 0, 0);
        if (SPLIT) {
          acc[mi][ni] = __builtin_amdgcn_mfma_f32_16x16x32_bf16(af[mi], bfl[ni], acc[mi][ni], 0, 0, 0);
          acc[mi][ni] = __builtin_amdgcn_mfma_f32_16x16x32_bf16(afl[mi], bfr[ni], acc[mi][ni], 0, 0, 0);
        }
      }
  }

#pragma unroll
  for (int mi = 0; mi < 4; mi++) {
    int m = m0 + wy * 64 + mi * 16 + quad * 4;
#pragma unroll
    for (int ni = 0; ni < 4; ni++) {
      int n = n0 + wx * 64 + ni * 16 + ln;
      if (OUT16) {
        ushort_t* cp = (ushort_t*)Cp + (size_t)m * N + n;
#pragma unroll
        for (int r = 0; r < 4; r++) cp[(size_t)r * N] = f2bf(acc[mi][ni][r]);
      } else {
        float* cp = (float*)Cp + (size_t)m * N + n;
#pragma unroll
        for (int r = 0; r < 4; r++) cp[(size_t)r * N] = acc[mi][ni][r];
      }
    }
  }
}

// ---------------- K fake-quant: per-column stats over 2048 rows -----------
__global__ __launch_bounds__(256) void kquant(float* __restrict__ KV) {
  __shared__ float s[2048];
  __shared__ float red[256];
  const int c = blockIdx.x, tid = threadIdx.x;
  float x[8];
#pragma unroll
  for (int i = 0; i < 8; i++) {
    x[i] = KV[(size_t)(tid + i * 256) * 2048 + c];
    s[tid + i * 256] = x[i];
  }
  __syncthreads();
  for (int k = 2; k <= 2048; k <<= 1)
    for (int j = k >> 1; j > 0; j >>= 1) {
      for (int i = tid; i < 2048; i += 256) {
        int l = i ^ j;
        if (l > i) {
          float a = s[i], b2 = s[l];
          bool up = ((i & k) == 0);
          if ((a > b2) == up) { s[i] = b2; s[l] = a; }
        }
      }
      __syncthreads();
    }
  float lower = s[1]    + 0.0235f * (s[2]    - s[1]);
  float upper = s[2045] + 0.9765f * (s[2046] - s[2045]);
  float med   = s[1023];
  float mx = -__builtin_inff(), mn = __builtin_inff();
#pragma unroll
  for (int i = 0; i < 8; i++) {
    bool m = (x[i] <= lower) | (x[i] >= upper);
    float t = m ? med : x[i];
    mx = fmaxf(mx, t);
    mn = fminf(mn, t);
  }
  __syncthreads();
  red[tid] = mx; __syncthreads();
  for (int off = 128; off > 0; off >>= 1) {
    if (tid < off) red[tid] = fmaxf(red[tid], red[tid + off]);
    __syncthreads();
  }
  mx = red[0]; __syncthreads();
  red[tid] = mn; __syncthreads();
  for (int off = 128; off > 0; off >>= 1) {
    if (tid < off) red[tid] = fminf(red[tid], red[tid + off]);
    __syncthreads();
  }
  mn = red[0];
  float qx = 15.0f / (mx - mn);
  float offv = mn * qx;
#pragma unroll
  for (int i = 0; i < 8; i++) {
    bool m = (x[i] <= lower) | (x[i] >= upper);
    float inp = m ? 0.f : x[i];
    float q = rintf(qx * inp - offv);
    q = fminf(fmaxf(q, 0.f), 15.f);
    float deq = (q + offv) / qx;
    float o = m ? x[i] : deq;
    if (!__builtin_isfinite(o)) o = 0.f;
    KV[(size_t)(tid + i * 256) * 2048 + c] = o;
  }
}

// ---------------- V fake-quant: per-row stats; writes bf16 rows -----------
__global__ __launch_bounds__(256) void vquant(const float* __restrict__ KV,
                                              ushort_t* __restrict__ vrow) {
  __shared__ float s[1024];
  __shared__ float red[256];
  const int rrow = blockIdx.x, tid = threadIdx.x;
  float x[4];
#pragma unroll
  for (int i = 0; i < 4; i++) {
    x[i] = KV[(size_t)rrow * 2048 + 1024 + tid + i * 256];
    s[tid + i * 256] = x[i];
  }
  __syncthreads();
  for (int k = 2; k <= 1024; k <<= 1)
    for (int j = k >> 1; j > 0; j >>= 1) {
      for (int i = tid; i < 1024; i += 256) {
        int l = i ^ j;
        if (l > i) {
          float a = s[i], b2 = s[l];
          bool up = ((i & k) == 0);
          if ((a > b2) == up) { s[i] = b2; s[l] = a; }
        }
      }
      __syncthreads();
    }
  float lower = s[0]    + 0.5115f * (s[1]    - s[0]);
  float upper = s[1022] + 0.4885f * (s[1023] - s[1022]);
  float med   = s[511];
  float mx = -__builtin_inff(), mn = __builtin_inff();
#pragma unroll
  for (int i = 0; i < 4; i++) {
    bool m = (x[i] <= lower) | (x[i] >= upper);
    float t = m ? med : x[i];
    mx = fmaxf(mx, t);
    mn = fminf(mn, t);
  }
  __syncthreads();
  red[tid] = mx; __syncthreads();
  for (int off = 128; off > 0; off >>= 1) {
    if (tid < off) red[tid] = fmaxf(red[tid], red[tid + off]);
    __syncthreads();
  }
  mx = red[0]; __syncthreads();
  red[tid] = mn; __syncthreads();
  for (int off = 128; off > 0; off >>= 1) {
    if (tid < off) red[tid] = fminf(red[tid], red[tid + off]);
    __syncthreads();
  }
  mn = red[0];
  float qx = 15.0f / (mx - mn);
  float offv = mn * qx;
#pragma unroll
  for (int i = 0; i < 4; i++) {
    bool m = (x[i] <= lower) | (x[i] >= upper);
    float inp = m ? 0.f : x[i];
    float q = rintf(qx * inp - offv);
    q = fminf(fmaxf(q, 0.f), 15.f);
    float deq = (q + offv) / qx;
    float o = m ? x[i] : deq;
    if (!__builtin_isfinite(o)) o = 0.f;
    vrow[(size_t)rrow * 1024 + tid + i * 256] = f2bf(o);
  }
}

// ---------------- V transpose: vrow(2048,1024) -> vb(B,KVH,128,1024) ------
__global__ __launch_bounds__(256) void vtrans(const ushort_t* __restrict__ vrow,
                                              ushort_t* __restrict__ vb) {
  __shared__ ushort_t T[64 * 65];
  const int c0 = blockIdx.x * 64, r0 = blockIdx.y * 64;
  const int b = r0 >> 10, sbase = r0 & 1023;
#pragma unroll
  for (int i = 0; i < 2; i++) {
    int idx = threadIdx.x + i * 256;
    int r = idx >> 3, c8 = (idx & 7) * 8;
    uint4 v = *(const uint4*)(vrow + (size_t)(r0 + r) * 1024 + c0 + c8);
    const ushort_t* p = (const ushort_t*)&v;
#pragma unroll
    for (int j = 0; j < 8; j++) T[r * 65 + c8 + j] = p[j];
  }
  __syncthreads();
#pragma unroll
  for (int i = 0; i < 2; i++) {
    int idx = threadIdx.x + i * 256;
    int c = idx >> 3, s8 = (idx & 7) * 8;
    ushort_t tmp[8];
#pragma unroll
    for (int j = 0; j < 8; j++) tmp[j] = T[(s8 + j) * 65 + c];
    int gc = c0 + c;  // h*128 + d
    size_t oa = ((size_t)(b * KVHEADS + (gc >> 7)) * HDIM + (gc & 127)) * S_LEN + sbase + s8;
    *(uint4*)(vb + oa) = *(const uint4*)tmp;
  }
}

// ---------------- RoPE Q: (B,S,NH*D) bf16 -> (B,NH,S,D) bf16, prescaled ---
__global__ __launch_bounds__(256) void rope_q(const ushort_t* __restrict__ Q,
                                              const int* __restrict__ pos,
                                              ushort_t* __restrict__ qb) {
  int t = blockIdx.x * 256 + threadIdx.x;
  int i = t & 63;
  int h = (t >> 6) & 31;
  int s = (t >> 11) & 1023;
  int b = t >> 21;
  int p = pos[b * S_LEN + s];
  float inv = expf(-9.210340371976184f * ((float)i * (1.0f / 64.0f)));
  float ang = (float)p * inv;
  float sn, cs;
  sincosf(ang, &sn, &cs);
  size_t base = ((size_t)(b * S_LEN + s)) * H_DIM + h * HDIM + i;
  float x1 = bf2f(Q[base]), x2 = bf2f(Q[base + 64]);
  const float sc = 0.08838834764831845f;  // 1/sqrt(128)
  size_t ob = (((size_t)(b * NHEADS + h)) * S_LEN + s) * HDIM + i;
  qb[ob]      = f2bf((x1 * cs - x2 * sn) * sc);
  qb[ob + 64] = f2bf((x2 * cs + x1 * sn) * sc);
}

// ---------------- RoPE K from combined KV fp32 ----------------------------
__global__ __launch_bounds__(256) void rope_k(const float* __restrict__ KV,
                                              const int* __restrict__ pos,
                                              ushort_t* __restrict__ kb) {
  int t = blockIdx.x * 256 + threadIdx.x;
  int i = t & 63;
  int h = (t >> 6) & 7;
  int s = (t >> 9) & 1023;
  int b = t >> 19;
  int p = pos[b * S_LEN + s];
  float inv = expf(-9.210340371976184f * ((float)i * (1.0f / 64.0f)));
  float ang = (float)p * inv;
  float sn, cs;
  sincosf(ang, &sn, &cs);
  size_t base = ((size_t)(b * S_LEN + s)) * 2048 + h * HDIM + i;
  float k1 = KV[base], k2 = KV[base + 64];
  size_t ob = (((size_t)(b * KVHEADS + h)) * S_LEN + s) * HDIM + i;
  kb[ob]      = f2bf(k1 * cs - k2 * sn);
  kb[ob + 64] = f2bf(k2 * cs + k1 * sn);
}

// ---------------- Flash attention (causal, GQA), 128-query tiles ----------
// grid (S/128, B*NH); block 256 = 4 waves; wave w owns queries q0+w*32..+31
__global__ __launch_bounds__(256) void attn_fwd(const ushort_t* __restrict__ qb,
                                                const ushort_t* __restrict__ kb,
                                                const ushort_t* __restrict__ vb,
                                                ushort_t* __restrict__ ob) {
  __shared__ short Ks[64 * 136];    // keys row-major [k][d], pad 8
  __shared__ short Vs[128 * 72];    // V^T [d][s], pad 8
  __shared__ short Ps[4 * 32 * 72]; // per-wave P [q][k], pad 8
  const int tid = threadIdx.x;
  const int wid = tid >> 6;
  const int lane = tid & 63;
  const int ln = lane & 15;
  const int quad = lane >> 4;
  const int q0 = blockIdx.x * 128;
  const int bh = blockIdx.y;
  const int b = bh >> 5, h = bh & 31, hk = h >> 2;

  // Q fragments (A-layout): 2 m-tiles of 16 queries each
  bf8 aq[2][4];
#pragma unroll
  for (int mi = 0; mi < 2; mi++) {
    const ushort_t* qrow =
        qb + (((size_t)(b * NHEADS + h)) * S_LEN + q0 + wid * 32 + mi * 16 + ln) * HDIM;
#pragma unroll
    for (int ks = 0; ks < 4; ks++) aq[mi][ks] = *(const bf8*)(qrow + ks * 32 + quad * 8);
  }

  f4 accO[2][8];
#pragma unroll
  for (int mi = 0; mi < 2; mi++)
#pragma unroll
    for (int i = 0; i < 8; i++) accO[mi][i] = (f4){0.f, 0.f, 0.f, 0.f};
  float mr[2][4], lr[2][4];
#pragma unroll
  for (int mi = 0; mi < 2; mi++)
#pragma unroll
    for (int r = 0; r < 4; r++) { mr[mi][r] = -__builtin_inff(); lr[mi][r] = 0.f; }

  const ushort_t* kbp = kb + ((size_t)(b * KVHEADS + hk)) * S_LEN * HDIM;
  const ushort_t* vbp = vb + ((size_t)(b * KVHEADS + hk)) * HDIM * S_LEN;

  const int ktiles = 2 * blockIdx.x + 2;
  for (int kt = 0; kt < ktiles; kt++) {
    const int k0 = kt * 64;
    __syncthreads();
#pragma unroll
    for (int cc = 0; cc < 4; cc++) {
      int idx = tid + cc * 256;
      int r = idx >> 4, c8 = idx & 15;  // K: key r, dims c8*8
      *(uint4*)&Ks[r * 136 + c8 * 8] = *(const uint4*)(kbp + (size_t)(k0 + r) * HDIM + c8 * 8);
      int d = idx >> 3, s8 = idx & 7;   // V^T: dim d, keys s8*8
      *(uint4*)&Vs[d * 72 + s8 * 8] = *(const uint4*)(vbp + (size_t)d * S_LEN + k0 + s8 * 8);
    }
    __syncthreads();

    if (q0 + wid * 32 + 31 < k0) continue;  // fully masked wave (uniform branch)

    // scores: 32 q x 64 k per wave
    f4 sc[2][4];
#pragma unroll
    for (int mi = 0; mi < 2; mi++)
#pragma unroll
      for (int nt = 0; nt < 4; nt++) sc[mi][nt] = (f4){0.f, 0.f, 0.f, 0.f};
#pragma unroll
    for (int nt = 0; nt < 4; nt++) {
      bf8 bk[4];
#pragma unroll
      for (int ks = 0; ks < 4; ks++)
        bk[ks] = *(const bf8*)&Ks[(nt * 16 + ln) * 136 + ks * 32 + quad * 8];
#pragma unroll
      for (int mi = 0; mi < 2; mi++)
#pragma unroll
        for (int ks = 0; ks < 4; ks++)
          sc[mi][nt] = __builtin_amdgcn_mfma_f32_16x16x32_bf16(aq[mi][ks], bk[ks], sc[mi][nt], 0, 0, 0);
    }
    // causal mask
#pragma unroll
    for (int mi = 0; mi < 2; mi++)
#pragma unroll
      for (int r = 0; r < 4; r++) {
        int mq = q0 + wid * 32 + mi * 16 + quad * 4 + r;
#pragma unroll
        for (int nt = 0; nt < 4; nt++) {
          int nk = k0 + nt * 16 + ln;
          if (nk > mq) sc[mi][nt][r] = -1e30f;
        }
      }
    // online softmax (8 independent rows/lane for ILP)
    float al[2][4];
#pragma unroll
    for (int mi = 0; mi < 2; mi++)
#pragma unroll
      for (int r = 0; r < 4; r++) {
        float tm = fmaxf(fmaxf(sc[mi][0][r], sc[mi][1][r]), fmaxf(sc[mi][2][r], sc[mi][3][r]));
        tm = fmaxf(tm, __shfl_xor(tm, 1));
        tm = fmaxf(tm, __shfl_xor(tm, 2));
        tm = fmaxf(tm, __shfl_xor(tm, 4));
        tm = fmaxf(tm, __shfl_xor(tm, 8));
        float mnew = fmaxf(mr[mi][r], tm);
        al[mi][r] = __expf(mr[mi][r] - mnew);
        mr[mi][r] = mnew;
        float ls = 0.f;
#pragma unroll
        for (int nt = 0; nt < 4; nt++) {
          float pp = __expf(sc[mi][nt][r] - mnew);
          sc[mi][nt][r] = pp;
          ls += pp;
        }
        ls += __shfl_xor(ls, 1);
        ls += __shfl_xor(ls, 2);
        ls += __shfl_xor(ls, 4);
        ls += __shfl_xor(ls, 8);
        lr[mi][r] = lr[mi][r] * al[mi][r] + ls;
      }
#pragma unroll
    for (int mi = 0; mi < 2; mi++)
#pragma unroll
      for (int dt = 0; dt < 8; dt++)
#pragma unroll
        for (int r = 0; r < 4; r++) accO[mi][dt][r] *= al[mi][r];
    // P (C-layout) -> wave-private LDS -> A-layout (no barrier needed)
#pragma unroll
    for (int mi = 0; mi < 2; mi++)
#pragma unroll
      for (int r = 0; r < 4; r++)
#pragma unroll
        for (int nt = 0; nt < 4; nt++)
          Ps[wid * 2304 + (mi * 16 + quad * 4 + r) * 72 + nt * 16 + ln] =
              (short)f2bf(sc[mi][nt][r]);
    bf8 ap[2][2];
#pragma unroll
    for (int mi = 0; mi < 2; mi++)
#pragma unroll
      for (int k2 = 0; k2 < 2; k2++)
        ap[mi][k2] = *(const bf8*)&Ps[wid * 2304 + (mi * 16 + ln) * 72 + k2 * 32 + quad * 8];
    // O += P @ V   (B-fragment read straight from V^T tile)
#pragma unroll
    for (int dt = 0; dt < 8; dt++)
#pragma unroll
      for (int k2 = 0; k2 < 2; k2++) {
        bf8 bv = *(const bf8*)&Vs[(dt * 16 + ln) * 72 + k2 * 32 + quad * 8];
#pragma unroll
        for (int mi = 0; mi < 2; mi++)
          accO[mi][dt] = __builtin_amdgcn_mfma_f32_16x16x32_bf16(ap[mi][k2], bv, accO[mi][dt], 0, 0, 0);
      }
  }
  // epilogue: write (B,S,NH*D) bf16
#pragma unroll
  for (int mi = 0; mi < 2; mi++)
#pragma unroll
    for (int r = 0; r < 4; r++) {
      float invl = 1.0f / lr[mi][r];
      int so = q0 + wid * 32 + mi * 16 + quad * 4 + r;
      size_t obase = ((size_t)(b * S_LEN + so)) * H_DIM + h * HDIM;
#pragma unroll
      for (int dt = 0; dt < 8; dt++)
        ob[obase + dt * 16 + ln] = f2bf(accO[mi][dt][r] * invl);
    }
}

extern "C" void kernel_launch(void* const* d_in, const int* in_sizes, int n_in,
                              void* d_out, int out_size, void* d_ws, size_t ws_size,
                              hipStream_t stream) {
  const float* hidden = (const float*)d_in[0];
  const float* Wq = (const float*)d_in[1];
  const float* Wk = (const float*)d_in[2];
  const float* Wv = (const float*)d_in[3];
  const float* Wo = (const float*)d_in[4];
  const int* pos = (const int*)d_in[5];
  float* outp = (float*)d_out;

  // workspace layout with lifetime-based reuse (~134 MB)
  char* ws = (char*)d_ws;
  ushort_t* wqh  = (ushort_t*)ws; ws += (size_t)4096 * 4096 * 2;  // Wq-hi, later Wo-hi
  ushort_t* hh   = (ushort_t*)ws; ws += (size_t)2048 * 4096 * 2;  // hidden hi; later ab
  ushort_t* hl   = (ushort_t*)ws; ws += (size_t)2048 * 4096 * 2;  // hidden lo; later vrow
  ushort_t* kvwh = (ushort_t*)ws; ws += (size_t)2048 * 4096 * 2;  // [Wk;Wv] hi; later qb
  ushort_t* kvwl = (ushort_t*)ws; ws += (size_t)2048 * 4096 * 2;  // [Wk;Wv] lo; later kb+vb
  ushort_t* Qf16 = (ushort_t*)ws; ws += (size_t)2048 * 4096 * 2;  // Q proj out (B,S,NH*D)
  float*    KVf  = (float*)ws;                                    // KV proj out (2048,2048) fp32

  ushort_t* qb   = kvwh;  // (B,NH,S,D)
  ushort_t* kb   = kvwl;  // (B,KVH,S,D)
  ushort_t* vb   = kvwl + (size_t)2 * KVHEADS * S_LEN * HDIM;  // (B,KVH,D,S)
  ushort_t* vrow = hl;    // quantized V rows (2048,1024) bf16
  ushort_t* ab   = hh;    // attn out (B,S,NH*D)

  // conversions
  cvt_split<<<8192, 256, 0, stream>>>(hidden, hh, hl, 2048 * 4096 / 4);
  cvt_hi<<<16384, 256, 0, stream>>>(Wq, wqh, 4096 * 4096 / 4);
  cvt_split<<<4096, 256, 0, stream>>>(Wk, kvwh, kvwl, 1024 * 4096 / 4);
  cvt_split<<<4096, 256, 0, stream>>>(Wv, kvwh + (size_t)1024 * 4096, kvwl + (size_t)1024 * 4096, 1024 * 4096 / 4);

  // projections
  gemm16<false, true><<<dim3(32, 16), 256, 0, stream>>>(hh, nullptr, wqh, nullptr, (void*)Qf16, 2048, 4096, 4096);
  gemm16<true, false><<<dim3(16, 16), 256, 0, stream>>>(hh, hl, kvwh, kvwl, (void*)KVf, 2048, 2048, 4096);

  // fake-quant
  kquant<<<1024, 256, 0, stream>>>(KVf);
  vquant<<<2048, 256, 0, stream>>>(KVf, vrow);   // hl reused as vrow (dead after KV GEMM)
  vtrans<<<dim3(16, 32), 256, 0, stream>>>(vrow, vb);

  // RoPE + layout + bf16 pack
  rope_q<<<16384, 256, 0, stream>>>(Qf16, pos, qb);
  rope_k<<<4096, 256, 0, stream>>>(KVf, pos, kb);

  // Wo conversion into wqh (Wq-hi dead after Q GEMM)
  cvt_hi<<<16384, 256, 0, stream>>>(Wo, wqh, 4096 * 4096 / 4);

  // attention (128-query tiles, V^T staged clean)
  attn_fwd<<<dim3(8, 64), 256, 0, stream>>>(qb, kb, vb, ab);

  // output projection
  gemm16<false, false><<<dim3(32, 16), 256, 0, stream>>>(ab, nullptr, wqh, nullptr, (void*)outp, 2048, 4096, 4096);
}

// Round 4
// 773.361 us; speedup vs baseline: 1.7624x; 1.1003x over previous
//
#include <hip/hip_runtime.h>

#define S_LEN 1024
#define B_SZ 2
#define H_DIM 4096
#define NHEADS 32
#define KVHEADS 8
#define HDIM 128
#define KV_DIM 1024
#define BS_C 2048

typedef _Float16 half8 __attribute__((ext_vector_type(8)));
typedef float f4 __attribute__((ext_vector_type(4)));
typedef unsigned short ushort_t;

static __device__ __forceinline__ ushort_t f2h(float x) {
  _Float16 h = (_Float16)x;
  return __builtin_bit_cast(unsigned short, h);
}
static __device__ __forceinline__ float h2f(ushort_t u) {
  return (float)__builtin_bit_cast(_Float16, u);
}

// async global->LDS, 16B per lane. LDS dest must be wave-uniform base + lane*16.
static __device__ __forceinline__ void gl2lds16(const void* g, void* l) {
  __builtin_amdgcn_global_load_lds(
      (const __attribute__((address_space(1))) unsigned int*)(unsigned long long)(uintptr_t)g,
      (__attribute__((address_space(3))) unsigned int*)(unsigned int)(uintptr_t)l,
      16, 0, 0);
}

// ---------------- fp32 -> fp16 conversion --------------------------------
__global__ __launch_bounds__(256) void cvt16(const float* __restrict__ x,
                                             ushort_t* __restrict__ h, int n4) {
  int i = blockIdx.x * 256 + threadIdx.x;
  if (i >= n4) return;
  float4 v = ((const float4*)x)[i];
  uint2 hp;
  hp.x = (unsigned)f2h(v.x) | ((unsigned)f2h(v.y) << 16);
  hp.y = (unsigned)f2h(v.z) | ((unsigned)f2h(v.w) << 16);
  ((uint2*)h)[i] = hp;
}

// ---------------- fused QKV GEMM: (2048x4096) @ (6144x4096)^T -------------
// cols 0..4095 -> Qout fp16 (2048x4096); cols 4096..6143 -> KVout fp32 (2048x2048)
__global__ __launch_bounds__(256) void gemm_qkv(const ushort_t* __restrict__ Ahg,
                                                const ushort_t* __restrict__ Bhg,
                                                ushort_t* __restrict__ Qout,
                                                float* __restrict__ KVout) {
  __shared__ short Ah[128 * 32];
  __shared__ short Bh[128 * 32];
  const int K = 4096;
  const int tid = threadIdx.x;
  const int wid = tid >> 6;
  const int lane = tid & 63;
  const int ln = lane & 15;
  const int quad = lane >> 4;
  const int wx = wid & 1, wy = wid >> 1;
  const int m0 = blockIdx.y * 128, n0 = blockIdx.x * 128;
  const int sr = tid >> 2, sc = (tid & 3) * 8;

  const ushort_t* ap0 = Ahg + (size_t)(m0 + sr) * K + sc;
  const ushort_t* bp0 = Bhg + (size_t)(n0 + sr) * K + sc;
  const size_t rs = (size_t)64 * K;

  f4 acc[4][4];
#pragma unroll
  for (int i = 0; i < 4; i++)
#pragma unroll
    for (int j = 0; j < 4; j++) acc[i][j] = (f4){0.f, 0.f, 0.f, 0.f};

  for (int kk = 0; kk < K; kk += 32) {
    gl2lds16(ap0 + kk,      &Ah[tid * 8]);
    gl2lds16(ap0 + kk + rs, &Ah[2048 + tid * 8]);
    gl2lds16(bp0 + kk,      &Bh[tid * 8]);
    gl2lds16(bp0 + kk + rs, &Bh[2048 + tid * 8]);
    __syncthreads();

    half8 af[4], bfr[4];
#pragma unroll
    for (int mi = 0; mi < 4; mi++)
      af[mi] = *(const half8*)&Ah[(wy * 64 + mi * 16 + ln) * 32 + quad * 8];
#pragma unroll
    for (int ni = 0; ni < 4; ni++)
      bfr[ni] = *(const half8*)&Bh[(wx * 64 + ni * 16 + ln) * 32 + quad * 8];
    __syncthreads();

#pragma unroll
    for (int mi = 0; mi < 4; mi++)
#pragma unroll
      for (int ni = 0; ni < 4; ni++)
        acc[mi][ni] = __builtin_amdgcn_mfma_f32_16x16x32_f16(af[mi], bfr[ni], acc[mi][ni], 0, 0, 0);
  }

#pragma unroll
  for (int mi = 0; mi < 4; mi++) {
    int m = m0 + wy * 64 + mi * 16 + quad * 4;
#pragma unroll
    for (int ni = 0; ni < 4; ni++) {
      int n = n0 + wx * 64 + ni * 16 + ln;
      if (n0 < 4096) {
        ushort_t* cp = Qout + (size_t)m * 4096 + n;
#pragma unroll
        for (int r = 0; r < 4; r++) cp[(size_t)r * 4096] = f2h(acc[mi][ni][r]);
      } else {
        float* cp = KVout + (size_t)m * 2048 + (n - 4096);
#pragma unroll
        for (int r = 0; r < 4; r++) cp[(size_t)r * 2048] = acc[mi][ni][r];
      }
    }
  }
}

// ---------------- O GEMM, split-K=2: (2048x4096) @ (4096x4096)^T ----------
__global__ __launch_bounds__(256) void gemm_o(const ushort_t* __restrict__ Ahg,
                                              const ushort_t* __restrict__ Bhg,
                                              float* __restrict__ C0,
                                              float* __restrict__ C1) {
  __shared__ short Ah[128 * 32];
  __shared__ short Bh[128 * 32];
  const int K = 4096;
  const int tid = threadIdx.x;
  const int wid = tid >> 6;
  const int lane = tid & 63;
  const int ln = lane & 15;
  const int quad = lane >> 4;
  const int wx = wid & 1, wy = wid >> 1;
  const int m0 = blockIdx.y * 128, n0 = blockIdx.x * 128;
  const int kz = blockIdx.z * 2048;
  const int sr = tid >> 2, sc = (tid & 3) * 8;

  const ushort_t* ap0 = Ahg + (size_t)(m0 + sr) * K + kz + sc;
  const ushort_t* bp0 = Bhg + (size_t)(n0 + sr) * K + kz + sc;
  const size_t rs = (size_t)64 * K;

  f4 acc[4][4];
#pragma unroll
  for (int i = 0; i < 4; i++)
#pragma unroll
    for (int j = 0; j < 4; j++) acc[i][j] = (f4){0.f, 0.f, 0.f, 0.f};

  for (int kk = 0; kk < 2048; kk += 32) {
    gl2lds16(ap0 + kk,      &Ah[tid * 8]);
    gl2lds16(ap0 + kk + rs, &Ah[2048 + tid * 8]);
    gl2lds16(bp0 + kk,      &Bh[tid * 8]);
    gl2lds16(bp0 + kk + rs, &Bh[2048 + tid * 8]);
    __syncthreads();

    half8 af[4], bfr[4];
#pragma unroll
    for (int mi = 0; mi < 4; mi++)
      af[mi] = *(const half8*)&Ah[(wy * 64 + mi * 16 + ln) * 32 + quad * 8];
#pragma unroll
    for (int ni = 0; ni < 4; ni++)
      bfr[ni] = *(const half8*)&Bh[(wx * 64 + ni * 16 + ln) * 32 + quad * 8];
    __syncthreads();

#pragma unroll
    for (int mi = 0; mi < 4; mi++)
#pragma unroll
      for (int ni = 0; ni < 4; ni++)
        acc[mi][ni] = __builtin_amdgcn_mfma_f32_16x16x32_f16(af[mi], bfr[ni], acc[mi][ni], 0, 0, 0);
  }

  float* Cp = blockIdx.z ? C1 : C0;
#pragma unroll
  for (int mi = 0; mi < 4; mi++) {
    int m = m0 + wy * 64 + mi * 16 + quad * 4;
#pragma unroll
    for (int ni = 0; ni < 4; ni++) {
      int n = n0 + wx * 64 + ni * 16 + ln;
      float* cp = Cp + (size_t)m * 4096 + n;
#pragma unroll
      for (int r = 0; r < 4; r++) cp[(size_t)r * 4096] = acc[mi][ni][r];
    }
  }
}

__global__ __launch_bounds__(256) void reduce2(float* __restrict__ out,
                                               const float* __restrict__ p1, int n4) {
  int i = blockIdx.x * 256 + threadIdx.x;
  if (i >= n4) return;
  float4 a = ((const float4*)out)[i];
  float4 b = ((const float4*)p1)[i];
  a.x += b.x; a.y += b.y; a.z += b.z; a.w += b.w;
  ((float4*)out)[i] = a;
}

// ---------------- K fake-quant: per-column stats over 2048 rows -----------
__global__ __launch_bounds__(256) void kquant(float* __restrict__ KV) {
  __shared__ float s[2048];
  __shared__ float red[256];
  const int c = blockIdx.x, tid = threadIdx.x;
  float x[8];
#pragma unroll
  for (int i = 0; i < 8; i++) {
    x[i] = KV[(size_t)(tid + i * 256) * 2048 + c];
    s[tid + i * 256] = x[i];
  }
  __syncthreads();
  for (int k = 2; k <= 2048; k <<= 1)
    for (int j = k >> 1; j > 0; j >>= 1) {
      for (int i = tid; i < 2048; i += 256) {
        int l = i ^ j;
        if (l > i) {
          float a = s[i], b2 = s[l];
          bool up = ((i & k) == 0);
          if ((a > b2) == up) { s[i] = b2; s[l] = a; }
        }
      }
      __syncthreads();
    }
  float lower = s[1]    + 0.0235f * (s[2]    - s[1]);
  float upper = s[2045] + 0.9765f * (s[2046] - s[2045]);
  float med   = s[1023];
  float mx = -__builtin_inff(), mn = __builtin_inff();
#pragma unroll
  for (int i = 0; i < 8; i++) {
    bool m = (x[i] <= lower) | (x[i] >= upper);
    float t = m ? med : x[i];
    mx = fmaxf(mx, t);
    mn = fminf(mn, t);
  }
  __syncthreads();
  red[tid] = mx; __syncthreads();
  for (int off = 128; off > 0; off >>= 1) {
    if (tid < off) red[tid] = fmaxf(red[tid], red[tid + off]);
    __syncthreads();
  }
  mx = red[0]; __syncthreads();
  red[tid] = mn; __syncthreads();
  for (int off = 128; off > 0; off >>= 1) {
    if (tid < off) red[tid] = fminf(red[tid], red[tid + off]);
    __syncthreads();
  }
  mn = red[0];
  float qx = 15.0f / (mx - mn);
  float offv = mn * qx;
#pragma unroll
  for (int i = 0; i < 8; i++) {
    bool m = (x[i] <= lower) | (x[i] >= upper);
    float inp = m ? 0.f : x[i];
    float q = rintf(qx * inp - offv);
    q = fminf(fmaxf(q, 0.f), 15.f);
    float deq = (q + offv) / qx;
    float o = m ? x[i] : deq;
    if (!__builtin_isfinite(o)) o = 0.f;
    KV[(size_t)(tid + i * 256) * 2048 + c] = o;
  }
}

// ---------------- V fake-quant: per-row stats; writes fp16 rows -----------
__global__ __launch_bounds__(256) void vquant(const float* __restrict__ KV,
                                              ushort_t* __restrict__ vrow) {
  __shared__ float s[1024];
  __shared__ float red[256];
  const int rrow = blockIdx.x, tid = threadIdx.x;
  float x[4];
#pragma unroll
  for (int i = 0; i < 4; i++) {
    x[i] = KV[(size_t)rrow * 2048 + 1024 + tid + i * 256];
    s[tid + i * 256] = x[i];
  }
  __syncthreads();
  for (int k = 2; k <= 1024; k <<= 1)
    for (int j = k >> 1; j > 0; j >>= 1) {
      for (int i = tid; i < 1024; i += 256) {
        int l = i ^ j;
        if (l > i) {
          float a = s[i], b2 = s[l];
          bool up = ((i & k) == 0);
          if ((a > b2) == up) { s[i] = b2; s[l] = a; }
        }
      }
      __syncthreads();
    }
  float lower = s[0]    + 0.5115f * (s[1]    - s[0]);
  float upper = s[1022] + 0.4885f * (s[1023] - s[1022]);
  float med   = s[511];
  float mx = -__builtin_inff(), mn = __builtin_inff();
#pragma unroll
  for (int i = 0; i < 4; i++) {
    bool m = (x[i] <= lower) | (x[i] >= upper);
    float t = m ? med : x[i];
    mx = fmaxf(mx, t);
    mn = fminf(mn, t);
  }
  __syncthreads();
  red[tid] = mx; __syncthreads();
  for (int off = 128; off > 0; off >>= 1) {
    if (tid < off) red[tid] = fmaxf(red[tid], red[tid + off]);
    __syncthreads();
  }
  mx = red[0]; __syncthreads();
  red[tid] = mn; __syncthreads();
  for (int off = 128; off > 0; off >>= 1) {
    if (tid < off) red[tid] = fminf(red[tid], red[tid + off]);
    __syncthreads();
  }
  mn = red[0];
  float qx = 15.0f / (mx - mn);
  float offv = mn * qx;
#pragma unroll
  for (int i = 0; i < 4; i++) {
    bool m = (x[i] <= lower) | (x[i] >= upper);
    float inp = m ? 0.f : x[i];
    float q = rintf(qx * inp - offv);
    q = fminf(fmaxf(q, 0.f), 15.f);
    float deq = (q + offv) / qx;
    float o = m ? x[i] : deq;
    if (!__builtin_isfinite(o)) o = 0.f;
    vrow[(size_t)rrow * 1024 + tid + i * 256] = f2h(o);
  }
}

// ---------------- V transpose: vrow(2048,1024) -> vb(B,KVH,128,1024) ------
__global__ __launch_bounds__(256) void vtrans(const ushort_t* __restrict__ vrow,
                                              ushort_t* __restrict__ vb) {
  __shared__ ushort_t T[64 * 65];
  const int c0 = blockIdx.x * 64, r0 = blockIdx.y * 64;
  const int b = r0 >> 10, sbase = r0 & 1023;
#pragma unroll
  for (int i = 0; i < 2; i++) {
    int idx = threadIdx.x + i * 256;
    int r = idx >> 3, c8 = (idx & 7) * 8;
    uint4 v = *(const uint4*)(vrow + (size_t)(r0 + r) * 1024 + c0 + c8);
    const ushort_t* p = (const ushort_t*)&v;
#pragma unroll
    for (int j = 0; j < 8; j++) T[r * 65 + c8 + j] = p[j];
  }
  __syncthreads();
#pragma unroll
  for (int i = 0; i < 2; i++) {
    int idx = threadIdx.x + i * 256;
    int c = idx >> 3, s8 = (idx & 7) * 8;
    ushort_t tmp[8];
#pragma unroll
    for (int j = 0; j < 8; j++) tmp[j] = T[(s8 + j) * 65 + c];
    int gc = c0 + c;  // h*128 + d
    size_t oa = ((size_t)(b * KVHEADS + (gc >> 7)) * HDIM + (gc & 127)) * S_LEN + sbase + s8;
    *(uint4*)(vb + oa) = *(const uint4*)tmp;
  }
}

// ---------------- RoPE Q: (B,S,NH*D) fp16 -> (B,NH,S,D) fp16, prescaled ---
__global__ __launch_bounds__(256) void rope_q(const ushort_t* __restrict__ Q,
                                              const int* __restrict__ pos,
                                              ushort_t* __restrict__ qb) {
  int t = blockIdx.x * 256 + threadIdx.x;
  int i = t & 63;
  int h = (t >> 6) & 31;
  int s = (t >> 11) & 1023;
  int b = t >> 21;
  int p = pos[b * S_LEN + s];
  float inv = expf(-9.210340371976184f * ((float)i * (1.0f / 64.0f)));
  float ang = (float)p * inv;
  float sn, cs;
  sincosf(ang, &sn, &cs);
  size_t base = ((size_t)(b * S_LEN + s)) * H_DIM + h * HDIM + i;
  float x1 = h2f(Q[base]), x2 = h2f(Q[base + 64]);
  const float sc = 0.08838834764831845f;  // 1/sqrt(128)
  size_t ob = (((size_t)(b * NHEADS + h)) * S_LEN + s) * HDIM + i;
  qb[ob]      = f2h((x1 * cs - x2 * sn) * sc);
  qb[ob + 64] = f2h((x2 * cs + x1 * sn) * sc);
}

// ---------------- RoPE K from combined KV fp32 ----------------------------
__global__ __launch_bounds__(256) void rope_k(const float* __restrict__ KV,
                                              const int* __restrict__ pos,
                                              ushort_t* __restrict__ kb) {
  int t = blockIdx.x * 256 + threadIdx.x;
  int i = t & 63;
  int h = (t >> 6) & 7;
  int s = (t >> 9) & 1023;
  int b = t >> 19;
  int p = pos[b * S_LEN + s];
  float inv = expf(-9.210340371976184f * ((float)i * (1.0f / 64.0f)));
  float ang = (float)p * inv;
  float sn, cs;
  sincosf(ang, &sn, &cs);
  size_t base = ((size_t)(b * S_LEN + s)) * 2048 + h * HDIM + i;
  float k1 = KV[base], k2 = KV[base + 64];
  size_t ob = (((size_t)(b * KVHEADS + h)) * S_LEN + s) * HDIM + i;
  kb[ob]      = f2h(k1 * cs - k2 * sn);
  kb[ob + 64] = f2h(k2 * cs + k1 * sn);
}

// ---------------- Flash attention (causal, GQA), 128-query tiles ----------
__global__ __launch_bounds__(256) void attn_fwd(const ushort_t* __restrict__ qb,
                                                const ushort_t* __restrict__ kb,
                                                const ushort_t* __restrict__ vb,
                                                ushort_t* __restrict__ ob) {
  __shared__ short Ks[64 * 136];    // keys row-major [k][d], pad 8
  __shared__ short Vs[128 * 72];    // V^T [d][s], pad 8
  __shared__ short Ps[4 * 32 * 72]; // per-wave P [q][k], pad 8
  const int tid = threadIdx.x;
  const int wid = tid >> 6;
  const int lane = tid & 63;
  const int ln = lane & 15;
  const int quad = lane >> 4;
  const int q0 = blockIdx.x * 128;
  const int bh = blockIdx.y;
  const int b = bh >> 5, h = bh & 31, hk = h >> 2;

  half8 aq[2][4];
#pragma unroll
  for (int mi = 0; mi < 2; mi++) {
    const ushort_t* qrow =
        qb + (((size_t)(b * NHEADS + h)) * S_LEN + q0 + wid * 32 + mi * 16 + ln) * HDIM;
#pragma unroll
    for (int ks = 0; ks < 4; ks++) aq[mi][ks] = *(const half8*)(qrow + ks * 32 + quad * 8);
  }

  f4 accO[2][8];
#pragma unroll
  for (int mi = 0; mi < 2; mi++)
#pragma unroll
    for (int i = 0; i < 8; i++) accO[mi][i] = (f4){0.f, 0.f, 0.f, 0.f};
  float mr[2][4], lr[2][4];
#pragma unroll
  for (int mi = 0; mi < 2; mi++)
#pragma unroll
    for (int r = 0; r < 4; r++) { mr[mi][r] = -__builtin_inff(); lr[mi][r] = 0.f; }

  const ushort_t* kbp = kb + ((size_t)(b * KVHEADS + hk)) * S_LEN * HDIM;
  const ushort_t* vbp = vb + ((size_t)(b * KVHEADS + hk)) * HDIM * S_LEN;

  const int ktiles = 2 * blockIdx.x + 2;
  for (int kt = 0; kt < ktiles; kt++) {
    const int k0 = kt * 64;
    __syncthreads();
#pragma unroll
    for (int cc = 0; cc < 4; cc++) {
      int idx = tid + cc * 256;
      int r = idx >> 4, c8 = idx & 15;
      *(uint4*)&Ks[r * 136 + c8 * 8] = *(const uint4*)(kbp + (size_t)(k0 + r) * HDIM + c8 * 8);
      int d = idx >> 3, s8 = idx & 7;
      *(uint4*)&Vs[d * 72 + s8 * 8] = *(const uint4*)(vbp + (size_t)d * S_LEN + k0 + s8 * 8);
    }
    __syncthreads();

    if (q0 + wid * 32 + 31 < k0) continue;  // fully masked wave (uniform branch)

    f4 sc[2][4];
#pragma unroll
    for (int mi = 0; mi < 2; mi++)
#pragma unroll
      for (int nt = 0; nt < 4; nt++) sc[mi][nt] = (f4){0.f, 0.f, 0.f, 0.f};
#pragma unroll
    for (int nt = 0; nt < 4; nt++) {
      half8 bk[4];
#pragma unroll
      for (int ks = 0; ks < 4; ks++)
        bk[ks] = *(const half8*)&Ks[(nt * 16 + ln) * 136 + ks * 32 + quad * 8];
#pragma unroll
      for (int mi = 0; mi < 2; mi++)
#pragma unroll
        for (int ks = 0; ks < 4; ks++)
          sc[mi][nt] = __builtin_amdgcn_mfma_f32_16x16x32_f16(aq[mi][ks], bk[ks], sc[mi][nt], 0, 0, 0);
    }
#pragma unroll
    for (int mi = 0; mi < 2; mi++)
#pragma unroll
      for (int r = 0; r < 4; r++) {
        int mq = q0 + wid * 32 + mi * 16 + quad * 4 + r;
#pragma unroll
        for (int nt = 0; nt < 4; nt++) {
          int nk = k0 + nt * 16 + ln;
          if (nk > mq) sc[mi][nt][r] = -1e30f;
        }
      }
    float al[2][4];
#pragma unroll
    for (int mi = 0; mi < 2; mi++)
#pragma unroll
      for (int r = 0; r < 4; r++) {
        float tm = fmaxf(fmaxf(sc[mi][0][r], sc[mi][1][r]), fmaxf(sc[mi][2][r], sc[mi][3][r]));
        tm = fmaxf(tm, __shfl_xor(tm, 1));
        tm = fmaxf(tm, __shfl_xor(tm, 2));
        tm = fmaxf(tm, __shfl_xor(tm, 4));
        tm = fmaxf(tm, __shfl_xor(tm, 8));
        float mnew = fmaxf(mr[mi][r], tm);
        al[mi][r] = __expf(mr[mi][r] - mnew);
        mr[mi][r] = mnew;
        float ls = 0.f;
#pragma unroll
        for (int nt = 0; nt < 4; nt++) {
          float pp = __expf(sc[mi][nt][r] - mnew);
          sc[mi][nt][r] = pp;
          ls += pp;
        }
        ls += __shfl_xor(ls, 1);
        ls += __shfl_xor(ls, 2);
        ls += __shfl_xor(ls, 4);
        ls += __shfl_xor(ls, 8);
        lr[mi][r] = lr[mi][r] * al[mi][r] + ls;
      }
#pragma unroll
    for (int mi = 0; mi < 2; mi++)
#pragma unroll
      for (int dt = 0; dt < 8; dt++)
#pragma unroll
        for (int r = 0; r < 4; r++) accO[mi][dt][r] *= al[mi][r];
#pragma unroll
    for (int mi = 0; mi < 2; mi++)
#pragma unroll
      for (int r = 0; r < 4; r++)
#pragma unroll
        for (int nt = 0; nt < 4; nt++)
          Ps[wid * 2304 + (mi * 16 + quad * 4 + r) * 72 + nt * 16 + ln] =
              (short)f2h(sc[mi][nt][r]);
    half8 ap[2][2];
#pragma unroll
    for (int mi = 0; mi < 2; mi++)
#pragma unroll
      for (int k2 = 0; k2 < 2; k2++)
        ap[mi][k2] = *(const half8*)&Ps[wid * 2304 + (mi * 16 + ln) * 72 + k2 * 32 + quad * 8];
#pragma unroll
    for (int dt = 0; dt < 8; dt++)
#pragma unroll
      for (int k2 = 0; k2 < 2; k2++) {
        half8 bv = *(const half8*)&Vs[(dt * 16 + ln) * 72 + k2 * 32 + quad * 8];
#pragma unroll
        for (int mi = 0; mi < 2; mi++)
          accO[mi][dt] = __builtin_amdgcn_mfma_f32_16x16x32_f16(ap[mi][k2], bv, accO[mi][dt], 0, 0, 0);
      }
  }
#pragma unroll
  for (int mi = 0; mi < 2; mi++)
#pragma unroll
    for (int r = 0; r < 4; r++) {
      float invl = 1.0f / lr[mi][r];
      int so = q0 + wid * 32 + mi * 16 + quad * 4 + r;
      size_t obase = ((size_t)(b * S_LEN + so)) * H_DIM + h * HDIM;
#pragma unroll
      for (int dt = 0; dt < 8; dt++)
        ob[obase + dt * 16 + ln] = f2h(accO[mi][dt][r] * invl);
    }
}

extern "C" void kernel_launch(void* const* d_in, const int* in_sizes, int n_in,
                              void* d_out, int out_size, void* d_ws, size_t ws_size,
                              hipStream_t stream) {
  const float* hidden = (const float*)d_in[0];
  const float* Wq = (const float*)d_in[1];
  const float* Wk = (const float*)d_in[2];
  const float* Wv = (const float*)d_in[3];
  const float* Wo = (const float*)d_in[4];
  const int* pos = (const int*)d_in[5];
  float* outp = (float*)d_out;

  // workspace layout (~113 MB) with lifetime-based reuse
  char* ws = (char*)d_ws;
  ushort_t* Wall = (ushort_t*)ws; ws += (size_t)6144 * 4096 * 2;  // [Wq;Wk;Wv] fp16; later Wo fp16 + qb
  ushort_t* hh   = (ushort_t*)ws; ws += (size_t)2048 * 4096 * 2;  // hidden fp16; later ab
  ushort_t* Qf16 = (ushort_t*)ws; ws += (size_t)2048 * 4096 * 2;  // Q proj out; later P1 (w/ KVf)
  float*    KVf  = (float*)ws;    ws += (size_t)2048 * 2048 * 4;  // KV proj out fp32
  ushort_t* vrow = (ushort_t*)ws; ws += (size_t)2048 * 1024 * 2;  // quantized V rows fp16
  ushort_t* kb   = (ushort_t*)ws; ws += (size_t)2048 * 1024 * 2;  // (B,KVH,S,D) fp16
  ushort_t* vb   = (ushort_t*)ws;                                 // (B,KVH,D,S) fp16

  ushort_t* Woh = Wall;                               // Wo fp16 (after QKV GEMM)
  ushort_t* qb  = Wall + (size_t)4096 * 4096;         // (B,NH,S,D), overlays Wk/Wv fp16
  ushort_t* ab  = hh;                                 // attn out (B,S,NH*D)
  float*    P1  = (float*)Qf16;                       // split-K partial, overlays Qf16+KVf

  // conversions to fp16
  cvt16<<<8192, 256, 0, stream>>>(hidden, hh, 2048 * 4096 / 4);
  cvt16<<<16384, 256, 0, stream>>>(Wq, Wall, 4096 * 4096 / 4);
  cvt16<<<4096, 256, 0, stream>>>(Wk, Wall + (size_t)4096 * 4096, 1024 * 4096 / 4);
  cvt16<<<4096, 256, 0, stream>>>(Wv, Wall + (size_t)5120 * 4096, 1024 * 4096 / 4);

  // fused QKV projection
  gemm_qkv<<<dim3(48, 16), 256, 0, stream>>>(hh, Wall, Qf16, KVf);

  // fake-quant (exact order statistics)
  kquant<<<1024, 256, 0, stream>>>(KVf);
  vquant<<<2048, 256, 0, stream>>>(KVf, vrow);
  vtrans<<<dim3(16, 32), 256, 0, stream>>>(vrow, vb);

  // RoPE + layout (qb overlays dead Wk/Wv region)
  rope_q<<<16384, 256, 0, stream>>>(Qf16, pos, qb);
  rope_k<<<4096, 256, 0, stream>>>(KVf, pos, kb);

  // Wo conversion into Wall head (Wq fp16 dead)
  cvt16<<<16384, 256, 0, stream>>>(Wo, Woh, 4096 * 4096 / 4);

  // attention
  attn_fwd<<<dim3(8, 64), 256, 0, stream>>>(qb, kb, vb, ab);

  // output projection, split-K=2 (z=0 -> outp, z=1 -> P1), then reduce
  gemm_o<<<dim3(32, 16, 2), 256, 0, stream>>>(ab, Woh, outp, P1);
  reduce2<<<8192, 256, 0, stream>>>(outp, P1, 2048 * 4096 / 4);
}